// Round 1
// 2729.199 us; speedup vs baseline: 1.1870x; 1.1870x over previous
//
#include <hip/hip_runtime.h>
#include <hip/hip_bf16.h>
#include <math.h>

#define T_LEN 512
#define LAT   1024
#define D_DIM 512
#define NH    8
#define HD    64
#define FF_D  2048
#define NL    8
#define NQ    16

typedef _Float16 f16x4 __attribute__((ext_vector_type(4)));
typedef _Float16 f16x8 __attribute__((ext_vector_type(8)));
typedef float    f32x4 __attribute__((ext_vector_type(4)));

// ---------------------------------------------------------------------------
// Workspace layout (float offsets)
// ---------------------------------------------------------------------------
#define WS_QFPRE    0
#define WS_G        131072
#define WS_QF       2097152
#define WS_TA       2621440
#define WS_HIDG     3145728            // 2048 guard floats before hidden
#define WS_HID      3147776
#define WS_CONV     3672064
#define WS_H        4196352
#define WS_X        4458496
#define WS_QB       4720640
#define WS_KB       4982784
#define WS_VB       5244928
#define WS_ATT      5507072
#define WS_FF       5769216
#define WS_BSUM     6817792
#define WS_HOUT     6819840            // guard 1024 at 6818816, post at 7344128
#define WS_UP       7348224            // guard 3072 at 7345152, post at 8396800
#define WS_DEC0     8400384            // guard 512  at 8399872, post at 8924672
#define WS_T1       8925440            // guard 256  at 8925184, post at 11022592
#define WS_T2       11022976           // guard 128  at 11022848, post at 17314432
#define WS_W2UP     17314560           // 6291456 floats -> f16 hi/lo planes (exact fit)
#define WS_W2D1     23606016           // 3145728
#define WS_W2D2     26751744           // 589824
#define WS_W2D3     27341568           // 122880
#define WS_T3       31457344           // guard 64 at 31457280, post at 47185984
#define WS_W2D4     47186048           // 24576 -> ends 47210624
#define WS_T4       0                  // aliases phase-A region (dead by then)
// dec0 transposed f16 weights: aliases t2 data region (dec0 runs before d2
// writes t2; needs 3670016 floats < 6291456 region)
#define WS_DEC0B16  11022976
// split-K partials: alias t3 data region (dead until dw3 gemm writes it)
#define WS_PART     31457344

// ---------------------------------------------------------------------------
// Zero the guard rows (ws is poisoned 0xAA before every launch)
// ---------------------------------------------------------------------------
__global__ void k_zero_guards(float* __restrict__ ws) {
    const int offs[13] = {3145728, 6818816, 7344128, 7345152, 8396800,
                          8399872, 8924672, 8925184, 11022592, 11022848,
                          17314432, 31457280, 47185984};
    const int lens[13] = {2048, 1024, 1024, 3072, 3072,
                          512, 512, 256, 256, 128,
                          128, 64, 64};
    int r = blockIdx.x;
    for (int i = threadIdx.x; i < lens[r]; i += 256) ws[offs[r] + i] = 0.f;
}

// ---------------------------------------------------------------------------
// Gathers
// ---------------------------------------------------------------------------
__global__ __launch_bounds__(256) void k_gather(const int* __restrict__ codes,
                                                const float* __restrict__ emb_first,
                                                const float* __restrict__ emb_rest,
                                                float* __restrict__ qf_pre,
                                                float* __restrict__ G) {
    int idx = blockIdx.x * 256 + threadIdx.x;
    int c = idx & 255;
    int r = (idx >> 8) & 15;
    int t = idx >> 12;
    if (t >= T_LEN) return;
    if (r == 0) {
        int code = codes[t];
        qf_pre[t * 256 + c] = emb_first[code * 256 + c];
    } else {
        int n = r - 1;
        int code = codes[(n + 1) * T_LEN + t];
        G[t * 3840 + n * 256 + c] = emb_rest[(n * 2048 + code) * 256 + c];
    }
}

__global__ void k_bias_sum(const float* __restrict__ pr_b, float* __restrict__ out) {
    int d = blockIdx.x * 256 + threadIdx.x;
    if (d >= LAT) return;
    float s = 0.f;
    for (int n = 0; n < NQ - 1; n++) s += pr_b[n * LAT + d];
    out[d] = s;
}

// ---------------------------------------------------------------------------
// convT weight transform -> TRANSPOSED f16 hi/lo planes [N=s*Cout][K3=3*Cin].
// Same math as the old fp32 k_wt, but emits BT[col][rowk] split into hi/lo
// halves for the fp16x3 MFMA path. Each thread owns 1 col x 32 rowk (64 B
// per plane, line-aligned since K3*2 is a multiple of 64).
// ---------------------------------------------------------------------------
__global__ __launch_bounds__(256) void k_wt16(const float* __restrict__ w,
                                              _Float16* __restrict__ bth,
                                              _Float16* __restrict__ btl,
                                              int Cin, int Cout, int s, int pad_a) {
    int K3 = 3 * Cin;
    int col = blockIdx.x * 64 + (threadIdx.x & 63);
    int rk0 = blockIdx.y * 128 + (threadIdx.x >> 6) * 32;
    if (rk0 >= K3) return;
    int p = col / Cout, co = col - p * Cout;
    int kk0 = (pad_a - p) % s;
    if (kk0 < 0) kk0 += s;
    int cp = (p + kk0 - pad_a) / s;
    size_t ob = (size_t)col * K3 + rk0;
    for (int rb = 0; rb < 32; rb += 4) {
        f16x4 h, l;
#pragma unroll
        for (int j2 = 0; j2 < 4; ++j2) {
            int rowk = rk0 + rb + j2;
            int j = rowk / Cin, ci = rowk - j * Cin;
            int d = j - 1;
            float v = 0.f;
            if (d == cp) v = w[((size_t)kk0 * Cin + ci) * Cout + co];
            else if (d == cp + 1) v = w[((size_t)(kk0 + s) * Cin + ci) * Cout + co];
            _Float16 hh = (_Float16)v;
            h[j2] = hh;
            l[j2] = (_Float16)(v - (float)hh);
        }
        *(f16x4*)(bth + ob + rb) = h;
        *(f16x4*)(btl + ob + rb) = l;
    }
}

// Plain transpose+split for dec0 conv weights: [K][N] fp32 -> [N][K] f16 hi/lo
__global__ __launch_bounds__(256) void k_bt16(const float* __restrict__ w,
                                              _Float16* __restrict__ bth,
                                              _Float16* __restrict__ btl,
                                              int K, int N) {
    int col = blockIdx.x * 64 + (threadIdx.x & 63);
    int rk0 = blockIdx.y * 128 + (threadIdx.x >> 6) * 32;
    size_t ob = (size_t)col * K + rk0;
    for (int rb = 0; rb < 32; rb += 4) {
        f16x4 h, l;
#pragma unroll
        for (int j2 = 0; j2 < 4; ++j2) {
            float v = w[(size_t)(rk0 + rb + j2) * N + col];
            _Float16 hh = (_Float16)v;
            h[j2] = hh;
            l[j2] = (_Float16)(v - (float)hh);
        }
        *(f16x4*)(bth + ob + rb) = h;
        *(f16x4*)(btl + ob + rb) = l;
    }
}

__device__ __forceinline__ float apply_act(float v, int act) {
    if (act == 1) return 0.5f * v * (1.0f + erff(v * 0.70710678118654752440f));
    if (act == 2) return v > 0.f ? v : expm1f(v);
    return v;
}

// ---------------------------------------------------------------------------
// fp16x3 MFMA GEMM (Ootomo split: ah*bh + ah*bl + al*bh; ~fp32 precision).
// Tile 128x64, BK=64 fp32, 256 threads = 4 waves arranged 2(M) x 2(N);
// each wave owns 64x32 = 4x2 16x16 fragments. A (fp32, windowed lda) is
// split hi/lo on the fly into swizzled LDS; B comes from pre-transposed
// f16 planes [N][Kfull]. LDS swizzle: slot ^= (row&7) on [row][128B] rows
// (the m214-proven pattern for per-lane-row ds_read_b128).
// ---------------------------------------------------------------------------
__global__ __launch_bounds__(256) void k_gemm16(const float* __restrict__ A, int lda,
                                                const _Float16* __restrict__ BTh,
                                                const _Float16* __restrict__ BTl, int ldb,
                                                const float* __restrict__ bias, unsigned bmask,
                                                float* __restrict__ C,
                                                float* __restrict__ part, long mn,
                                                int N, int klen, int act) {
    __shared__ _Float16 Ash[128 * 64];
    __shared__ _Float16 Asl[128 * 64];
    __shared__ _Float16 Bsh[64 * 64];
    __shared__ _Float16 Bsl[64 * 64];
    int tid = threadIdx.x;
    int m0 = blockIdx.x * 128, n0 = blockIdx.y * 64;
    int kz = blockIdx.z * klen;
    const float* Ab = A + kz;
    int lane = tid & 63, wv = tid >> 6;
    int wr = wv >> 1, wc = wv & 1;
    int fr = lane & 15, g = lane >> 4;

    f32x4 acc[4][2];
#pragma unroll
    for (int m = 0; m < 4; ++m)
#pragma unroll
        for (int n = 0; n < 2; ++n)
#pragma unroll
            for (int r = 0; r < 4; ++r) acc[m][n][r] = 0.f;

    int nk = klen >> 6;
    for (int t = 0; t < nk; ++t) {
        int k0 = t << 6;
        // ---- stage A: 128x64 fp32 -> hi/lo f16, swizzled ----
#pragma unroll
        for (int i2 = 0; i2 < 8; ++i2) {
            int c = tid + 256 * i2;
            int row = c >> 4, kc = c & 15;
            float4 v = *(const float4*)(Ab + (size_t)(m0 + row) * lda + k0 + (kc << 2));
            f16x4 h, l;
            float vv[4] = {v.x, v.y, v.z, v.w};
#pragma unroll
            for (int j = 0; j < 4; ++j) {
                _Float16 hh = (_Float16)vv[j];
                h[j] = hh;
                l[j] = (_Float16)(vv[j] - (float)hh);
            }
            int off = row * 64 + (((kc >> 1) ^ (row & 7)) << 3) + ((kc & 1) << 2);
            *(f16x4*)(Ash + off) = h;
            *(f16x4*)(Asl + off) = l;
        }
        // ---- stage B: 64 cols x 64 k f16 hi/lo, swizzled ----
#pragma unroll
        for (int i2 = 0; i2 < 2; ++i2) {
            int c = tid + 256 * i2;
            int col = c >> 3, s = c & 7;
            size_t goff = (size_t)(n0 + col) * ldb + kz + k0 + (s << 3);
            f16x8 hv = *(const f16x8*)(BTh + goff);
            f16x8 lv = *(const f16x8*)(BTl + goff);
            int off = col * 64 + ((s ^ (col & 7)) << 3);
            *(f16x8*)(Bsh + off) = hv;
            *(f16x8*)(Bsl + off) = lv;
        }
        __syncthreads();
        // ---- compute: 2 x (12 ds_read_b128 + 24 mfma) ----
#pragma unroll
        for (int kk = 0; kk < 2; ++kk) {
            f16x8 ah[4], al[4], bh[2], bl[2];
#pragma unroll
            for (int m = 0; m < 4; ++m) {
                int row = wr * 64 + m * 16 + fr;
                int off = row * 64 + ((((kk << 2) + g) ^ (row & 7)) << 3);
                ah[m] = *(const f16x8*)(Ash + off);
                al[m] = *(const f16x8*)(Asl + off);
            }
#pragma unroll
            for (int n = 0; n < 2; ++n) {
                int col = wc * 32 + n * 16 + fr;
                int off = col * 64 + ((((kk << 2) + g) ^ (col & 7)) << 3);
                bh[n] = *(const f16x8*)(Bsh + off);
                bl[n] = *(const f16x8*)(Bsl + off);
            }
#pragma unroll
            for (int m = 0; m < 4; ++m)
#pragma unroll
                for (int n = 0; n < 2; ++n) {
                    acc[m][n] = __builtin_amdgcn_mfma_f32_16x16x32_f16(ah[m], bh[n], acc[m][n], 0, 0, 0);
                    acc[m][n] = __builtin_amdgcn_mfma_f32_16x16x32_f16(ah[m], bl[n], acc[m][n], 0, 0, 0);
                    acc[m][n] = __builtin_amdgcn_mfma_f32_16x16x32_f16(al[m], bh[n], acc[m][n], 0, 0, 0);
                }
        }
        __syncthreads();
    }
    // ---- epilogue: C/D frag layout col=lane&15, row=(lane>>4)*4+r ----
    if (part) {
        float* op = part + (size_t)blockIdx.z * mn;
#pragma unroll
        for (int m = 0; m < 4; ++m) {
            int row = m0 + wr * 64 + m * 16 + (g << 2);
#pragma unroll
            for (int n = 0; n < 2; ++n) {
                int col = n0 + wc * 32 + n * 16 + fr;
#pragma unroll
                for (int r = 0; r < 4; ++r)
                    op[(size_t)(row + r) * N + col] = acc[m][n][r];
            }
        }
    } else {
#pragma unroll
        for (int m = 0; m < 4; ++m) {
            int row = m0 + wr * 64 + m * 16 + (g << 2);
#pragma unroll
            for (int n = 0; n < 2; ++n) {
                int col = n0 + wc * 32 + n * 16 + fr;
                float bv = bias ? bias[col & bmask] : 0.f;
#pragma unroll
                for (int r = 0; r < 4; ++r) {
                    float v = acc[m][n][r] + bv;
                    v = apply_act(v, act);
                    C[(size_t)(row + r) * N + col] = v;
                }
            }
        }
    }
}

// ---------------------------------------------------------------------------
// fp32 GEMM core (kept for RVQ / transformer): double-buffered LDS,
// register-staged global loads. Tile TM x 64, 256 threads, K-step 16.
// ---------------------------------------------------------------------------
template <int TM>
__device__ __forceinline__ void gemm_core(const float* __restrict__ A, int lda,
                                          const float* __restrict__ B, int N,
                                          int klen, int m0, int n0,
                                          float (&acc)[TM / 16][4]) {
    constexpr int RM = TM / 16;
    constexpr int AR = TM * 16 / 256;
    __shared__ float As[2][16][TM + 4];
    __shared__ float Bs[2][16][64];
    int tid = threadIdx.x;
    int tx = tid & 15, ty = tid >> 4;
    int bc = tid & 63, br0 = tid >> 6;
    int arow[AR], akk[AR];
#pragma unroll
    for (int i = 0; i < AR; i++) { int idx = tid + 256 * i; arow[i] = idx >> 4; akk[i] = idx & 15; }
    float areg[AR], breg[4];
#pragma unroll
    for (int i = 0; i < AR; i++) areg[i] = A[(size_t)(m0 + arow[i]) * lda + akk[i]];
#pragma unroll
    for (int i = 0; i < 4; i++) breg[i] = B[(size_t)(br0 + 4 * i) * N + n0 + bc];
#pragma unroll
    for (int i = 0; i < AR; i++) As[0][akk[i]][arow[i]] = areg[i];
#pragma unroll
    for (int i = 0; i < 4; i++) Bs[0][br0 + 4 * i][bc] = breg[i];
    __syncthreads();
    int nk = klen >> 4;
    for (int t = 0; t < nk; t++) {
        int cur = t & 1;
        if (t + 1 < nk) {
            int k0 = (t + 1) << 4;
#pragma unroll
            for (int i = 0; i < AR; i++) areg[i] = A[(size_t)(m0 + arow[i]) * lda + k0 + akk[i]];
#pragma unroll
            for (int i = 0; i < 4; i++) breg[i] = B[(size_t)(k0 + br0 + 4 * i) * N + n0 + bc];
        }
#pragma unroll
        for (int kk = 0; kk < 16; kk++) {
            float a[RM], b[4];
#pragma unroll
            for (int i = 0; i < RM; i++) a[i] = As[cur][kk][ty * RM + i];
#pragma unroll
            for (int j = 0; j < 4; j++) b[j] = Bs[cur][kk][tx * 4 + j];
#pragma unroll
            for (int i = 0; i < RM; i++)
#pragma unroll
                for (int j = 0; j < 4; j++) acc[i][j] += a[i] * b[j];
        }
        if (t + 1 < nk) {
            int nxt = cur ^ 1;
#pragma unroll
            for (int i = 0; i < AR; i++) As[nxt][akk[i]][arow[i]] = areg[i];
#pragma unroll
            for (int i = 0; i < 4; i++) Bs[nxt][br0 + 4 * i][bc] = breg[i];
            __syncthreads();
        }
    }
}

// If part != null: raw partial write to part + z*mn (epilogue done in k_reduce).
template <int TM>
__global__ __launch_bounds__(256) void k_gemm2(const float* __restrict__ A, int lda,
                                               const float* __restrict__ B,
                                               const float* __restrict__ bias, unsigned bmask,
                                               const float* __restrict__ res,
                                               const float* __restrict__ scale,
                                               float* __restrict__ C,
                                               float* __restrict__ part, long mn,
                                               int N, int klen, int act) {
    constexpr int RM = TM / 16;
    float acc[RM][4] = {};
    int m0 = blockIdx.x * TM, n0 = blockIdx.y * 64;
    int kz = blockIdx.z * klen;
    gemm_core<TM>(A + kz, lda, B + (size_t)kz * N, N, klen, m0, n0, acc);
    int tid = threadIdx.x;
    int tx = tid & 15, ty = tid >> 4;
    if (part) {
        float* out = part + (size_t)blockIdx.z * mn;
#pragma unroll
        for (int i = 0; i < RM; i++)
#pragma unroll
            for (int j = 0; j < 4; j++)
                out[(size_t)(m0 + ty * RM + i) * N + n0 + tx * 4 + j] = acc[i][j];
    } else {
#pragma unroll
        for (int i = 0; i < RM; i++) {
            int row = m0 + ty * RM + i;
#pragma unroll
            for (int j = 0; j < 4; j++) {
                int col = n0 + tx * 4 + j;
                float v = acc[i][j];
                if (bias) v += bias[col & bmask];
                v = apply_act(v, act);
                if (scale) v *= scale[col];
                if (res) v += res[(size_t)row * N + col];
                C[(size_t)row * N + col] = v;
            }
        }
    }
}

// Fused QKV with split-K=2: z = which*2 + s; raw partials.
__global__ __launch_bounds__(256) void k_qkv(const float* __restrict__ A,
                                             const float* __restrict__ B0,
                                             const float* __restrict__ B1,
                                             const float* __restrict__ B2,
                                             float* __restrict__ part) {
    int which = blockIdx.z >> 1, s = blockIdx.z & 1;
    const float* B = which == 0 ? B0 : (which == 1 ? B1 : B2);
    float acc[2][4] = {};
    int m0 = blockIdx.x * 32, n0 = blockIdx.y * 64;
    int kz = s * 256;
    gemm_core<32>(A + kz, 512, B + (size_t)kz * 512, 512, 256, m0, n0, acc);
    int tid = threadIdx.x;
    int tx = tid & 15, ty = tid >> 4;
    float* out = part + (size_t)blockIdx.z * (512 * 512);
#pragma unroll
    for (int i = 0; i < 2; i++)
#pragma unroll
        for (int j = 0; j < 4; j++)
            out[(size_t)(m0 + ty * 2 + i) * 512 + n0 + tx * 4 + j] = acc[i][j];
}

// ---------------------------------------------------------------------------
// Split-K reduce + epilogue (bias -> act -> scale -> res)
// ---------------------------------------------------------------------------
__global__ __launch_bounds__(256) void k_reduce(const float* __restrict__ part, long mn, int S,
                                                const float* __restrict__ bias, unsigned bmask,
                                                const float* __restrict__ res,
                                                const float* __restrict__ scale,
                                                float* __restrict__ C, int N, int act) {
    long idx = ((long)blockIdx.x * 256 + threadIdx.x) * 4;
    if (idx >= mn) return;
    float4 v = *(const float4*)(part + idx);
    for (int s2 = 1; s2 < S; s2++) {
        float4 u = *(const float4*)(part + (size_t)s2 * mn + idx);
        v.x += u.x; v.y += u.y; v.z += u.z; v.w += u.w;
    }
    int col = (int)(idx % N);
    float vv[4] = {v.x, v.y, v.z, v.w};
#pragma unroll
    for (int j = 0; j < 4; j++) {
        float t = vv[j];
        int c = col + j;
        if (bias) t += bias[c & bmask];
        t = apply_act(t, act);
        if (scale) t *= scale[c];
        if (res) t += res[idx + j];
        vv[j] = t;
    }
    *(float4*)(C + idx) = make_float4(vv[0], vv[1], vv[2], vv[3]);
}

__global__ __launch_bounds__(256) void k_reduce_qkv(const float* __restrict__ part,
                                                    float* __restrict__ q,
                                                    float* __restrict__ k,
                                                    float* __restrict__ v) {
    const long mn = 262144;
    int w = blockIdx.y;
    long idx = ((long)blockIdx.x * 256 + threadIdx.x) * 4;
    float4 a = *(const float4*)(part + (size_t)(2 * w) * mn + idx);
    float4 b = *(const float4*)(part + (size_t)(2 * w + 1) * mn + idx);
    float* C = w == 0 ? q : (w == 1 ? k : v);
    *(float4*)(C + idx) = make_float4(a.x + b.x, a.y + b.y, a.z + b.z, a.w + b.w);
}

// ---------------------------------------------------------------------------
// RMSNorm rows of x[M,N]
// ---------------------------------------------------------------------------
__global__ __launch_bounds__(256) void k_rms(const float* __restrict__ x,
                                             const float* __restrict__ g,
                                             float* __restrict__ y, int N) {
    int row = blockIdx.x;
    const float* xr = x + (size_t)row * N;
    int tid = threadIdx.x;
    float s = 0.f;
    for (int i = tid; i < N; i += 256) { float v = xr[i]; s += v * v; }
#pragma unroll
    for (int off = 32; off; off >>= 1) s += __shfl_xor(s, off);
    __shared__ float red[4];
    if ((tid & 63) == 0) red[tid >> 6] = s;
    __syncthreads();
    s = red[0] + red[1] + red[2] + red[3];
    float r = 1.0f / sqrtf(s / (float)N + 1e-6f);
    for (int i = tid; i < N; i += 256) y[(size_t)row * N + i] = xr[i] * r * g[i];
}

// ---------------------------------------------------------------------------
// Fused qk-norm + RoPE for q AND k (blockIdx.y picks buffer)
// ---------------------------------------------------------------------------
__global__ void k_qkrope2(float* __restrict__ q, float* __restrict__ k,
                          const float* __restrict__ gq, const float* __restrict__ gk) {
    int bid = blockIdx.x;
    int t = bid >> 3, h = bid & 7;
    int d = threadIdx.x;
    float* p = (blockIdx.y == 0 ? q : k) + (size_t)t * D_DIM + h * HD;
    const float* g = blockIdx.y == 0 ? gq : gk;
    float val = p[d];
    float s = val * val;
#pragma unroll
    for (int off = 32; off; off >>= 1) s += __shfl_xor(s, off);
    float r = 1.0f / sqrtf(s * (1.0f / 64.0f) + 1e-6f);
    float y = val * r * g[d];
    int dm = d & 31;
    double inv = pow(10000.0, -(double)dm / 32.0);
    double ang = (double)t * inv;
    float c = (float)cos(ang);
    float sn = (float)sin(ang);
    float partner = __shfl_xor(y, 32);
    float out = (d < 32) ? (y * c - partner * sn) : (y * c + partner * sn);
    p[d] = out;
}

// ---------------------------------------------------------------------------
// Causal attention, one block per (t, h)
// ---------------------------------------------------------------------------
__global__ __launch_bounds__(256) void k_attn(const float* __restrict__ q,
                                              const float* __restrict__ k,
                                              const float* __restrict__ v,
                                              float* __restrict__ o) {
    int bid = blockIdx.x;
    int t = bid >> 3, h = bid & 7;
    __shared__ float qs[64];
    __shared__ float sc[T_LEN];
    __shared__ float red[8];
    int tid = threadIdx.x;
    if (tid < 64) qs[tid] = q[(size_t)t * D_DIM + h * HD + tid];
    __syncthreads();
    int nk = t + 1;
    for (int kk = tid; kk < nk; kk += 256) {
        const float* kr = k + (size_t)kk * D_DIM + h * HD;
        float dot = 0.f;
#pragma unroll
        for (int d = 0; d < HD; d++) dot += qs[d] * kr[d];
        sc[kk] = dot * 0.125f;
    }
    __syncthreads();
    float m = -3.4e38f;
    for (int i = tid; i < nk; i += 256) m = fmaxf(m, sc[i]);
#pragma unroll
    for (int off = 32; off; off >>= 1) m = fmaxf(m, __shfl_xor(m, off));
    if ((tid & 63) == 0) red[tid >> 6] = m;
    __syncthreads();
    m = fmaxf(fmaxf(red[0], red[1]), fmaxf(red[2], red[3]));
    float ssum = 0.f;
    for (int i = tid; i < nk; i += 256) { float e = expf(sc[i] - m); sc[i] = e; ssum += e; }
#pragma unroll
    for (int off = 32; off; off >>= 1) ssum += __shfl_xor(ssum, off);
    if ((tid & 63) == 0) red[4 + (tid >> 6)] = ssum;
    __syncthreads();
    ssum = red[4] + red[5] + red[6] + red[7];
    float inv = 1.0f / ssum;
    int d = tid & 63, part = tid >> 6;
    float a0 = 0.f;
    for (int i = part; i < nk; i += 4) a0 += sc[i] * v[(size_t)i * D_DIM + h * HD + d];
    __syncthreads();
    sc[part * 64 + d] = a0;
    __syncthreads();
    if (tid < 64) {
        float r = (sc[tid] + sc[64 + tid] + sc[128 + tid] + sc[192 + tid]) * inv;
        o[(size_t)t * D_DIM + h * HD + tid] = r;
    }
}

// ---------------------------------------------------------------------------
// Final conv: Cin=32 -> 1, K=7 SAME, clip
// ---------------------------------------------------------------------------
__global__ __launch_bounds__(256) void k_conv_fin(const float* __restrict__ x,
                                                  const float* __restrict__ w,
                                                  const float* __restrict__ b,
                                                  float* __restrict__ y, int n) {
    __shared__ float xs[262 * 33];
    __shared__ float wsm[224];
    int tid = threadIdx.x;
    int o0 = blockIdx.x * 256;
    for (int i = tid; i < 262 * 32; i += 256) {
        int r = i >> 5, c = i & 31;
        int t = o0 - 3 + r;
        xs[r * 33 + c] = (t >= 0 && t < n) ? x[(size_t)t * 32 + c] : 0.f;
    }
    if (tid < 224) wsm[tid] = w[tid];
    __syncthreads();
    float acc = b[0];
#pragma unroll
    for (int kk = 0; kk < 7; kk++)
#pragma unroll
        for (int ci = 0; ci < 32; ci++)
            acc += xs[(tid + kk) * 33 + ci] * wsm[kk * 32 + ci];
    y[o0 + tid] = fminf(fmaxf(acc, -1.f), 1.f);
}

// ---------------------------------------------------------------------------
// Host helpers
// ---------------------------------------------------------------------------
static inline void gemmS64(hipStream_t st, const float* A, int lda, const float* B,
                           const float* bias, unsigned bmask, const float* res,
                           const float* scale, float* C, float* part,
                           int M, int N, int K, int S, int act) {
    long mn = (long)M * N;
    if (S > 1) {
        k_gemm2<64><<<dim3(M / 64, N / 64, S), 256, 0, st>>>(
            A, lda, B, nullptr, 0, nullptr, nullptr, nullptr, part, mn, N, K / S, 0);
        k_reduce<<<dim3((int)(mn / 1024)), 256, 0, st>>>(
            part, mn, S, bias, bmask, res, scale, C, N, act);
    } else {
        k_gemm2<64><<<dim3(M / 64, N / 64, 1), 256, 0, st>>>(
            A, lda, B, bias, bmask, res, scale, C, nullptr, mn, N, K, act);
    }
}
static inline void gemmS32(hipStream_t st, const float* A, int lda, const float* B,
                           const float* bias, unsigned bmask, const float* res,
                           const float* scale, float* C, float* part,
                           int M, int N, int K, int S, int act) {
    long mn = (long)M * N;
    if (S > 1) {
        k_gemm2<32><<<dim3(M / 32, N / 64, S), 256, 0, st>>>(
            A, lda, B, nullptr, 0, nullptr, nullptr, nullptr, part, mn, N, K / S, 0);
        k_reduce<<<dim3((int)(mn / 1024)), 256, 0, st>>>(
            part, mn, S, bias, bmask, res, scale, C, N, act);
    } else {
        k_gemm2<32><<<dim3(M / 32, N / 64, 1), 256, 0, st>>>(
            A, lda, B, bias, bmask, res, scale, C, nullptr, mn, N, K, act);
    }
}

extern "C" void kernel_launch(void* const* d_in, const int* in_sizes, int n_in,
                              void* d_out, int out_size, void* d_ws, size_t ws_size,
                              hipStream_t stream) {
    int i = 0;
    const int*   codes     = (const int*)  d_in[i++];
    const float* emb_first = (const float*)d_in[i++];
    const float* pf_w      = (const float*)d_in[i++];
    const float* pf_b      = (const float*)d_in[i++];
    const float* fo_w      = (const float*)d_in[i++];
    const float* fo_b      = (const float*)d_in[i++];
    const float* emb_rest  = (const float*)d_in[i++];
    const float* pr_w      = (const float*)d_in[i++];
    const float* pr_b      = (const float*)d_in[i++];
    const float* ro_w      = (const float*)d_in[i++];
    const float* ro_b      = (const float*)d_in[i++];
    const float* pre_w     = (const float*)d_in[i++];
    const float* pre_b     = (const float*)d_in[i++];
    const float* in_w      = (const float*)d_in[i++];
    const float* in_b      = (const float*)d_in[i++];
    const float* ln1       = (const float*)d_in[i++];
    const float* qw        = (const float*)d_in[i++];
    const float* kw        = (const float*)d_in[i++];
    const float* vw        = (const float*)d_in[i++];
    const float* ow        = (const float*)d_in[i++];
    const float* qn        = (const float*)d_in[i++];
    const float* kn        = (const float*)d_in[i++];
    const float* ls_a      = (const float*)d_in[i++];
    const float* ln2       = (const float*)d_in[i++];
    const float* w1        = (const float*)d_in[i++];
    const float* w2        = (const float*)d_in[i++];
    const float* ls_m      = (const float*)d_in[i++];
    const float* fn_w      = (const float*)d_in[i++];
    const float* out_w     = (const float*)d_in[i++];
    const float* out_b     = (const float*)d_in[i++];
    const float* up_w      = (const float*)d_in[i++];
    const float* up_b      = (const float*)d_in[i++];
    const float* dec0_w    = (const float*)d_in[i++];
    const float* dec0_b    = (const float*)d_in[i++];
    const float* dw1       = (const float*)d_in[i++];
    const float* db1       = (const float*)d_in[i++];
    const float* dw2       = (const float*)d_in[i++];
    const float* db2       = (const float*)d_in[i++];
    const float* dw3       = (const float*)d_in[i++];
    const float* db3       = (const float*)d_in[i++];
    const float* dw4       = (const float*)d_in[i++];
    const float* db4       = (const float*)d_in[i++];
    const float* fin_w     = (const float*)d_in[i++];
    const float* fin_b     = (const float*)d_in[i++];

    float* ws = (float*)d_ws;
    float* outp = (float*)d_out;

    float* qf_pre   = ws + WS_QFPRE;
    float* G        = ws + WS_G;
    float* qf       = ws + WS_QF;
    float* tA       = ws + WS_TA;
    float* hidden   = ws + WS_HID;
    float* conv_out = ws + WS_CONV;
    float* h        = ws + WS_H;
    float* x        = ws + WS_X;
    float* qb       = ws + WS_QB;
    float* kb       = ws + WS_KB;
    float* vb       = ws + WS_VB;
    float* attnb    = ws + WS_ATT;
    float* ff       = ws + WS_FF;
    float* bias_sum = ws + WS_BSUM;
    float* houtp    = ws + WS_HOUT;
    float* up_out   = ws + WS_UP;
    float* dec0_out = ws + WS_DEC0;
    float* t1       = ws + WS_T1;
    float* t2       = ws + WS_T2;
    float* t3       = ws + WS_T3;
    float* t4       = ws + WS_T4;
    float* part     = ws + WS_PART;

    // f16 hi/lo transposed weight planes (exact-fit aliases of old W2 regions)
    _Float16* BTup_h = (_Float16*)(ws + WS_W2UP);   _Float16* BTup_l = BTup_h + 2048 * 3072;
    _Float16* BTd1_h = (_Float16*)(ws + WS_W2D1);   _Float16* BTd1_l = BTd1_h + 2048 * 1536;
    _Float16* BTd2_h = (_Float16*)(ws + WS_W2D2);   _Float16* BTd2_l = BTd2_h + 768 * 768;
    _Float16* BTd3_h = (_Float16*)(ws + WS_W2D3);   _Float16* BTd3_l = BTd3_h + 320 * 384;
    _Float16* BTd4_h = (_Float16*)(ws + WS_W2D4);   _Float16* BTd4_l = BTd4_h + 128 * 192;
    _Float16* BTd0_h = (_Float16*)(ws + WS_DEC0B16);_Float16* BTd0_l = BTd0_h + 512 * 7168;

    // --- prep ---
    k_zero_guards<<<13, 256, 0, stream>>>(ws);
    k_wt16<<<dim3(32, 24), 256, 0, stream>>>(up_w, BTup_h, BTup_l, 1024, 1024, 2, 2);
    k_wt16<<<dim3(32, 12), 256, 0, stream>>>(dw1, BTd1_h, BTd1_l, 512, 256, 8, 11);
    k_wt16<<<dim3(12, 6), 256, 0, stream>>>(dw2, BTd2_h, BTd2_l, 256, 128, 6, 8);
    k_wt16<<<dim3(5, 3), 256, 0, stream>>>(dw3, BTd3_h, BTd3_l, 128, 64, 5, 7);
    k_wt16<<<dim3(2, 2), 256, 0, stream>>>(dw4, BTd4_h, BTd4_l, 64, 32, 4, 5);
    k_bt16<<<dim3(8, 56), 256, 0, stream>>>(dec0_w, BTd0_h, BTd0_l, 7168, 512);

    // --- RVQ decode ---
    k_gather<<<8192, 256, 0, stream>>>(codes, emb_first, emb_rest, qf_pre, G);
    k_bias_sum<<<4, 256, 0, stream>>>(pr_b, bias_sum);
    gemmS64(stream, qf_pre, 256, pf_w, pf_b, ~0u, nullptr, nullptr, tA, part, 512, 1024, 256, 2, 0);
    gemmS64(stream, tA, 1024, fo_w, fo_b, ~0u, nullptr, nullptr, qf, part, 512, 1024, 1024, 4, 0);
    gemmS64(stream, G, 3840, pr_w, bias_sum, ~0u, nullptr, nullptr, tA, part, 512, 1024, 3840, 8, 0);
    gemmS64(stream, tA, 1024, ro_w, ro_b, ~0u, qf, nullptr, hidden, part, 512, 1024, 1024, 4, 0);

    // --- causal pre-conv (k=3) via windowed GEMM ---
    gemmS64(stream, hidden - 2048, 1024, pre_w, pre_b, ~0u, nullptr, nullptr,
            conv_out, part, 512, 1024, 3072, 8, 0);

    // --- transformer input proj ---
    gemmS32(stream, conv_out, 1024, in_w, in_b, ~0u, nullptr, nullptr, h, part, 512, 512, 1024, 4, 0);

    // --- 8 transformer layers ---
    for (int l = 0; l < NL; l++) {
        const float* qw_l = qw + (size_t)l * D_DIM * D_DIM;
        const float* kw_l = kw + (size_t)l * D_DIM * D_DIM;
        const float* vw_l = vw + (size_t)l * D_DIM * D_DIM;
        const float* ow_l = ow + (size_t)l * D_DIM * D_DIM;
        const float* w1_l = w1 + (size_t)l * D_DIM * FF_D;
        const float* w2_l = w2 + (size_t)l * FF_D * D_DIM;

        k_rms<<<512, 256, 0, stream>>>(h, ln1 + l * D_DIM, x, D_DIM);
        k_qkv<<<dim3(16, 8, 6), 256, 0, stream>>>(x, qw_l, kw_l, vw_l, part);
        k_reduce_qkv<<<dim3(256, 3), 256, 0, stream>>>(part, qb, kb, vb);
        k_qkrope2<<<dim3(T_LEN * NH, 2), 64, 0, stream>>>(qb, kb, qn + l * HD, kn + l * HD);
        k_attn<<<T_LEN * NH, 256, 0, stream>>>(qb, kb, vb, attnb);
        gemmS32(stream, attnb, 512, ow_l, nullptr, 0, h, ls_a + l * D_DIM, h, part,
                512, 512, 512, 2, 0);
        k_rms<<<512, 256, 0, stream>>>(h, ln2 + l * D_DIM, x, D_DIM);
        gemmS64(stream, x, 512, w1_l, nullptr, 0, nullptr, nullptr, ff, part,
                512, 2048, 512, 2, 1);
        gemmS32(stream, ff, 2048, w2_l, nullptr, 0, h, ls_m + l * D_DIM, h, part,
                512, 512, 2048, 8, 0);
    }

    // --- final norm + out proj ---
    k_rms<<<512, 256, 0, stream>>>(h, fn_w, x, D_DIM);
    gemmS64(stream, x, 512, out_w, out_b, ~0u, nullptr, nullptr, houtp, part, 512, 1024, 512, 4, 0);

    // --- upsample x2 convT as GEMM (fp16x3 MFMA), elu; split-K=2 ---
    k_gemm16<<<dim3(4, 32, 2), 256, 0, stream>>>(houtp - 1024, 1024, BTup_h, BTup_l, 3072,
            nullptr, 0, nullptr, part, 1048576L, 2048, 1536, 0);
    k_reduce<<<1024, 256, 0, stream>>>(part, 1048576L, 2, up_b, 1023u, nullptr, nullptr,
            up_out, 2048, 2);

    // --- dec0 conv k=7 SAME via windowed GEMM (fp16x3 MFMA), elu; split-K=4 ---
    k_gemm16<<<dim3(8, 8, 4), 256, 0, stream>>>(up_out - 3072, 1024, BTd0_h, BTd0_l, 7168,
            nullptr, 0, nullptr, part, 524288L, 512, 1792, 0);
    k_reduce<<<512, 256, 0, stream>>>(part, 524288L, 4, dec0_b, ~0u, nullptr, nullptr,
            dec0_out, 512, 2);

    // --- SEANet convT chain as fp16x3 MFMA GEMMs, elu ---
    k_gemm16<<<dim3(8, 32, 1), 256, 0, stream>>>(dec0_out - 512, 512, BTd1_h, BTd1_l, 1536,
            db1, 255u, t1, nullptr, 0L, 2048, 1536, 2);
    k_gemm16<<<dim3(64, 12, 1), 256, 0, stream>>>(t1 - 256, 256, BTd2_h, BTd2_l, 768,
            db2, 127u, t2, nullptr, 0L, 768, 768, 2);
    k_gemm16<<<dim3(384, 5, 1), 256, 0, stream>>>(t2 - 128, 128, BTd3_h, BTd3_l, 384,
            db3, 63u, t3, nullptr, 0L, 320, 384, 2);
    k_gemm16<<<dim3(1920, 2, 1), 256, 0, stream>>>(t3 - 64, 64, BTd4_h, BTd4_l, 192,
            db4, 31u, t4, nullptr, 0L, 128, 192, 2);

    // --- final conv ---
    k_conv_fin<<<983040 / 256, 256, 0, stream>>>(t4, fin_w, fin_b, outp, 983040);
}

// Round 2
// 2033.232 us; speedup vs baseline: 1.5934x; 1.3423x over previous
//
#include <hip/hip_runtime.h>
#include <hip/hip_bf16.h>
#include <math.h>

#define T_LEN 512
#define LAT   1024
#define D_DIM 512
#define NH    8
#define HD    64
#define FF_D  2048
#define NL    8
#define NQ    16

typedef _Float16 f16x4 __attribute__((ext_vector_type(4)));
typedef _Float16 f16x8 __attribute__((ext_vector_type(8)));
typedef float    f32x4 __attribute__((ext_vector_type(4)));

// ---------------------------------------------------------------------------
// Workspace layout (float offsets)
// ---------------------------------------------------------------------------
#define WS_QFPRE    0
#define WS_G        131072
#define WS_QF       2097152
#define WS_TA       2621440
#define WS_HIDG     3145728            // 2048 guard floats before hidden
#define WS_HID      3147776
#define WS_CONV     3672064
#define WS_H        4196352
#define WS_X        4458496
#define WS_QB       4720640
#define WS_KB       4982784
#define WS_VB       5244928
#define WS_ATT      5507072
#define WS_FF       5769216
#define WS_BSUM     6817792
#define WS_HOUT     6819840            // guard 1024 at 6818816, post at 7344128
#define WS_UP       7348224            // guard 3072 at 7345152, post at 8396800
#define WS_DEC0     8400384            // guard 512  at 8399872, post at 8924672
#define WS_T1       8925440            // guard 256  at 8925184, post at 11022592
#define WS_T2       11022976           // guard 128  at 11022848, post at 17314432
#define WS_W2UP     17314560           // 6291456 floats -> f16 hi/lo planes (exact fit)
#define WS_W2D1     23606016           // 3145728
#define WS_W2D2     26751744           // 589824
#define WS_W2D3     27341568           // 122880
#define WS_T3       31457344           // guard 64 at 31457280, post at 47185984
#define WS_W2D4     47186048           // 24576 -> ends 47210624
#define WS_T4       0                  // aliases phase-A region (dead by then)
// dec0 transposed f16 weights: aliases t2 data region (dec0 runs before d2
// writes t2; needs 3670016 floats < 6291456 region)
#define WS_DEC0B16  11022976
// split-K partials: alias t3 data region (dead until dw3 gemm writes it)
#define WS_PART     31457344
// pr_w transposed f16 planes: after max part usage (31457344+8*524288=35651648),
// consumed during RVQ, overwritten much later by t3. 3932160 floats.
#define WS_BTPR     35651712
// RoPE cos/sin table: 2*16384 floats, after BTPR (ends 39583872)
#define WS_ROPE     39583872

// ---------------------------------------------------------------------------
// Zero the guard rows (ws is poisoned 0xAA before every launch)
// ---------------------------------------------------------------------------
__global__ void k_zero_guards(float* __restrict__ ws) {
    const int offs[13] = {3145728, 6818816, 7344128, 7345152, 8396800,
                          8399872, 8924672, 8925184, 11022592, 11022848,
                          17314432, 31457280, 47185984};
    const int lens[13] = {2048, 1024, 1024, 3072, 3072,
                          512, 512, 256, 256, 128,
                          128, 64, 64};
    int r = blockIdx.x;
    for (int i = threadIdx.x; i < lens[r]; i += 256) ws[offs[r] + i] = 0.f;
}

// ---------------------------------------------------------------------------
// Gathers
// ---------------------------------------------------------------------------
__global__ __launch_bounds__(256) void k_gather(const int* __restrict__ codes,
                                                const float* __restrict__ emb_first,
                                                const float* __restrict__ emb_rest,
                                                float* __restrict__ qf_pre,
                                                float* __restrict__ G) {
    int idx = blockIdx.x * 256 + threadIdx.x;
    int c = idx & 255;
    int r = (idx >> 8) & 15;
    int t = idx >> 12;
    if (t >= T_LEN) return;
    if (r == 0) {
        int code = codes[t];
        qf_pre[t * 256 + c] = emb_first[code * 256 + c];
    } else {
        int n = r - 1;
        int code = codes[(n + 1) * T_LEN + t];
        G[t * 3840 + n * 256 + c] = emb_rest[(n * 2048 + code) * 256 + c];
    }
}

__global__ void k_bias_sum(const float* __restrict__ pr_b, float* __restrict__ out) {
    int d = blockIdx.x * 256 + threadIdx.x;
    if (d >= LAT) return;
    float s = 0.f;
    for (int n = 0; n < NQ - 1; n++) s += pr_b[n * LAT + d];
    out[d] = s;
}

// RoPE cos/sin table: tab[0..16383]=cos(t*inv(dm)), tab[16384..]=sin
__global__ void k_rope_tab(float* __restrict__ tab) {
    int idx = blockIdx.x * 256 + threadIdx.x;
    int t = idx >> 5, dm = idx & 31;
    double inv = pow(10000.0, -(double)dm / 32.0);
    double ang = (double)t * inv;
    tab[idx] = (float)cos(ang);
    tab[16384 + idx] = (float)sin(ang);
}

// ---------------------------------------------------------------------------
// convT weight transform -> TRANSPOSED f16 hi/lo planes [N=s*Cout][K3=3*Cin].
// ---------------------------------------------------------------------------
__global__ __launch_bounds__(256) void k_wt16(const float* __restrict__ w,
                                              _Float16* __restrict__ bth,
                                              _Float16* __restrict__ btl,
                                              int Cin, int Cout, int s, int pad_a) {
    int K3 = 3 * Cin;
    int col = blockIdx.x * 64 + (threadIdx.x & 63);
    int rk0 = blockIdx.y * 128 + (threadIdx.x >> 6) * 32;
    if (rk0 >= K3) return;
    int p = col / Cout, co = col - p * Cout;
    int kk0 = (pad_a - p) % s;
    if (kk0 < 0) kk0 += s;
    int cp = (p + kk0 - pad_a) / s;
    size_t ob = (size_t)col * K3 + rk0;
    for (int rb = 0; rb < 32; rb += 4) {
        f16x4 h, l;
#pragma unroll
        for (int j2 = 0; j2 < 4; ++j2) {
            int rowk = rk0 + rb + j2;
            int j = rowk / Cin, ci = rowk - j * Cin;
            int d = j - 1;
            float v = 0.f;
            if (d == cp) v = w[((size_t)kk0 * Cin + ci) * Cout + co];
            else if (d == cp + 1) v = w[((size_t)(kk0 + s) * Cin + ci) * Cout + co];
            _Float16 hh = (_Float16)v;
            h[j2] = hh;
            l[j2] = (_Float16)(v - (float)hh);
        }
        *(f16x4*)(bth + ob + rb) = h;
        *(f16x4*)(btl + ob + rb) = l;
    }
}

// Plain transpose+split: [K][N] fp32 -> [N][K] f16 hi/lo
__global__ __launch_bounds__(256) void k_bt16(const float* __restrict__ w,
                                              _Float16* __restrict__ bth,
                                              _Float16* __restrict__ btl,
                                              int K, int N) {
    int col = blockIdx.x * 64 + (threadIdx.x & 63);
    int rk0 = blockIdx.y * 128 + (threadIdx.x >> 6) * 32;
    size_t ob = (size_t)col * K + rk0;
    for (int rb = 0; rb < 32; rb += 4) {
        f16x4 h, l;
#pragma unroll
        for (int j2 = 0; j2 < 4; ++j2) {
            float v = w[(size_t)(rk0 + rb + j2) * N + col];
            _Float16 hh = (_Float16)v;
            h[j2] = hh;
            l[j2] = (_Float16)(v - (float)hh);
        }
        *(f16x4*)(bth + ob + rb) = h;
        *(f16x4*)(btl + ob + rb) = l;
    }
}

__device__ __forceinline__ float apply_act(float v, int act) {
    if (act == 1) return 0.5f * v * (1.0f + erff(v * 0.70710678118654752440f));
    if (act == 2) return v > 0.f ? v : expm1f(v);
    return v;
}

// ---------------------------------------------------------------------------
// fp16x3 MFMA GEMM (Ootomo split: ah*bh + ah*bl + al*bh; ~fp32 precision).
// Tile 128x64, BK=64, 256 threads = 4 waves (2M x 2N), swizzled LDS.
// ---------------------------------------------------------------------------
__global__ __launch_bounds__(256) void k_gemm16(const float* __restrict__ A, int lda,
                                                const _Float16* __restrict__ BTh,
                                                const _Float16* __restrict__ BTl, int ldb,
                                                const float* __restrict__ bias, unsigned bmask,
                                                float* __restrict__ C,
                                                float* __restrict__ part, long mn,
                                                int N, int klen, int act) {
    __shared__ _Float16 Ash[128 * 64];
    __shared__ _Float16 Asl[128 * 64];
    __shared__ _Float16 Bsh[64 * 64];
    __shared__ _Float16 Bsl[64 * 64];
    int tid = threadIdx.x;
    int m0 = blockIdx.x * 128, n0 = blockIdx.y * 64;
    int kz = blockIdx.z * klen;
    const float* Ab = A + kz;
    int lane = tid & 63, wv = tid >> 6;
    int wr = wv >> 1, wc = wv & 1;
    int fr = lane & 15, g = lane >> 4;

    f32x4 acc[4][2];
#pragma unroll
    for (int m = 0; m < 4; ++m)
#pragma unroll
        for (int n = 0; n < 2; ++n)
#pragma unroll
            for (int r = 0; r < 4; ++r) acc[m][n][r] = 0.f;

    int nk = klen >> 6;
    for (int t = 0; t < nk; ++t) {
        int k0 = t << 6;
#pragma unroll
        for (int i2 = 0; i2 < 8; ++i2) {
            int c = tid + 256 * i2;
            int row = c >> 4, kc = c & 15;
            float4 v = *(const float4*)(Ab + (size_t)(m0 + row) * lda + k0 + (kc << 2));
            f16x4 h, l;
            float vv[4] = {v.x, v.y, v.z, v.w};
#pragma unroll
            for (int j = 0; j < 4; ++j) {
                _Float16 hh = (_Float16)vv[j];
                h[j] = hh;
                l[j] = (_Float16)(vv[j] - (float)hh);
            }
            int off = row * 64 + (((kc >> 1) ^ (row & 7)) << 3) + ((kc & 1) << 2);
            *(f16x4*)(Ash + off) = h;
            *(f16x4*)(Asl + off) = l;
        }
#pragma unroll
        for (int i2 = 0; i2 < 2; ++i2) {
            int c = tid + 256 * i2;
            int col = c >> 3, s = c & 7;
            size_t goff = (size_t)(n0 + col) * ldb + kz + k0 + (s << 3);
            f16x8 hv = *(const f16x8*)(BTh + goff);
            f16x8 lv = *(const f16x8*)(BTl + goff);
            int off = col * 64 + ((s ^ (col & 7)) << 3);
            *(f16x8*)(Bsh + off) = hv;
            *(f16x8*)(Bsl + off) = lv;
        }
        __syncthreads();
#pragma unroll
        for (int kk = 0; kk < 2; ++kk) {
            f16x8 ah[4], al[4], bh[2], bl[2];
#pragma unroll
            for (int m = 0; m < 4; ++m) {
                int row = wr * 64 + m * 16 + fr;
                int off = row * 64 + ((((kk << 2) + g) ^ (row & 7)) << 3);
                ah[m] = *(const f16x8*)(Ash + off);
                al[m] = *(const f16x8*)(Asl + off);
            }
#pragma unroll
            for (int n = 0; n < 2; ++n) {
                int col = wc * 32 + n * 16 + fr;
                int off = col * 64 + ((((kk << 2) + g) ^ (col & 7)) << 3);
                bh[n] = *(const f16x8*)(Bsh + off);
                bl[n] = *(const f16x8*)(Bsl + off);
            }
#pragma unroll
            for (int m = 0; m < 4; ++m)
#pragma unroll
                for (int n = 0; n < 2; ++n) {
                    acc[m][n] = __builtin_amdgcn_mfma_f32_16x16x32_f16(ah[m], bh[n], acc[m][n], 0, 0, 0);
                    acc[m][n] = __builtin_amdgcn_mfma_f32_16x16x32_f16(ah[m], bl[n], acc[m][n], 0, 0, 0);
                    acc[m][n] = __builtin_amdgcn_mfma_f32_16x16x32_f16(al[m], bh[n], acc[m][n], 0, 0, 0);
                }
        }
        __syncthreads();
    }
    if (part) {
        float* op = part + (size_t)blockIdx.z * mn;
#pragma unroll
        for (int m = 0; m < 4; ++m) {
            int row = m0 + wr * 64 + m * 16 + (g << 2);
#pragma unroll
            for (int n = 0; n < 2; ++n) {
                int col = n0 + wc * 32 + n * 16 + fr;
#pragma unroll
                for (int r = 0; r < 4; ++r)
                    op[(size_t)(row + r) * N + col] = acc[m][n][r];
            }
        }
    } else {
#pragma unroll
        for (int m = 0; m < 4; ++m) {
            int row = m0 + wr * 64 + m * 16 + (g << 2);
#pragma unroll
            for (int n = 0; n < 2; ++n) {
                int col = n0 + wc * 32 + n * 16 + fr;
                float bv = bias ? bias[col & bmask] : 0.f;
#pragma unroll
                for (int r = 0; r < 4; ++r) {
                    float v = acc[m][n][r] + bv;
                    v = apply_act(v, act);
                    C[(size_t)(row + r) * N + col] = v;
                }
            }
        }
    }
}

// ---------------------------------------------------------------------------
// fp32 GEMM core (kept for RVQ / transformer)
// ---------------------------------------------------------------------------
template <int TM>
__device__ __forceinline__ void gemm_core(const float* __restrict__ A, int lda,
                                          const float* __restrict__ B, int N,
                                          int klen, int m0, int n0,
                                          float (&acc)[TM / 16][4]) {
    constexpr int RM = TM / 16;
    constexpr int AR = TM * 16 / 256;
    __shared__ float As[2][16][TM + 4];
    __shared__ float Bs[2][16][64];
    int tid = threadIdx.x;
    int tx = tid & 15, ty = tid >> 4;
    int bc = tid & 63, br0 = tid >> 6;
    int arow[AR], akk[AR];
#pragma unroll
    for (int i = 0; i < AR; i++) { int idx = tid + 256 * i; arow[i] = idx >> 4; akk[i] = idx & 15; }
    float areg[AR], breg[4];
#pragma unroll
    for (int i = 0; i < AR; i++) areg[i] = A[(size_t)(m0 + arow[i]) * lda + akk[i]];
#pragma unroll
    for (int i = 0; i < 4; i++) breg[i] = B[(size_t)(br0 + 4 * i) * N + n0 + bc];
#pragma unroll
    for (int i = 0; i < AR; i++) As[0][akk[i]][arow[i]] = areg[i];
#pragma unroll
    for (int i = 0; i < 4; i++) Bs[0][br0 + 4 * i][bc] = breg[i];
    __syncthreads();
    int nk = klen >> 4;
    for (int t = 0; t < nk; t++) {
        int cur = t & 1;
        if (t + 1 < nk) {
            int k0 = (t + 1) << 4;
#pragma unroll
            for (int i = 0; i < AR; i++) areg[i] = A[(size_t)(m0 + arow[i]) * lda + k0 + akk[i]];
#pragma unroll
            for (int i = 0; i < 4; i++) breg[i] = B[(size_t)(k0 + br0 + 4 * i) * N + n0 + bc];
        }
#pragma unroll
        for (int kk = 0; kk < 16; kk++) {
            float a[RM], b[4];
#pragma unroll
            for (int i = 0; i < RM; i++) a[i] = As[cur][kk][ty * RM + i];
#pragma unroll
            for (int j = 0; j < 4; j++) b[j] = Bs[cur][kk][tx * 4 + j];
#pragma unroll
            for (int i = 0; i < RM; i++)
#pragma unroll
                for (int j = 0; j < 4; j++) acc[i][j] += a[i] * b[j];
        }
        if (t + 1 < nk) {
            int nxt = cur ^ 1;
#pragma unroll
            for (int i = 0; i < AR; i++) As[nxt][akk[i]][arow[i]] = areg[i];
#pragma unroll
            for (int i = 0; i < 4; i++) Bs[nxt][br0 + 4 * i][bc] = breg[i];
            __syncthreads();
        }
    }
}

template <int TM>
__global__ __launch_bounds__(256) void k_gemm2(const float* __restrict__ A, int lda,
                                               const float* __restrict__ B,
                                               const float* __restrict__ bias, unsigned bmask,
                                               const float* __restrict__ res,
                                               const float* __restrict__ scale,
                                               float* __restrict__ C,
                                               float* __restrict__ part, long mn,
                                               int N, int klen, int act) {
    constexpr int RM = TM / 16;
    float acc[RM][4] = {};
    int m0 = blockIdx.x * TM, n0 = blockIdx.y * 64;
    int kz = blockIdx.z * klen;
    gemm_core<TM>(A + kz, lda, B + (size_t)kz * N, N, klen, m0, n0, acc);
    int tid = threadIdx.x;
    int tx = tid & 15, ty = tid >> 4;
    if (part) {
        float* out = part + (size_t)blockIdx.z * mn;
#pragma unroll
        for (int i = 0; i < RM; i++)
#pragma unroll
            for (int j = 0; j < 4; j++)
                out[(size_t)(m0 + ty * RM + i) * N + n0 + tx * 4 + j] = acc[i][j];
    } else {
#pragma unroll
        for (int i = 0; i < RM; i++) {
            int row = m0 + ty * RM + i;
#pragma unroll
            for (int j = 0; j < 4; j++) {
                int col = n0 + tx * 4 + j;
                float v = acc[i][j];
                if (bias) v += bias[col & bmask];
                v = apply_act(v, act);
                if (scale) v *= scale[col];
                if (res) v += res[(size_t)row * N + col];
                C[(size_t)row * N + col] = v;
            }
        }
    }
}

// Fused QKV with split-K=2: z = which*2 + s; raw partials.
__global__ __launch_bounds__(256) void k_qkv(const float* __restrict__ A,
                                             const float* __restrict__ B0,
                                             const float* __restrict__ B1,
                                             const float* __restrict__ B2,
                                             float* __restrict__ part) {
    int which = blockIdx.z >> 1, s = blockIdx.z & 1;
    const float* B = which == 0 ? B0 : (which == 1 ? B1 : B2);
    float acc[2][4] = {};
    int m0 = blockIdx.x * 32, n0 = blockIdx.y * 64;
    int kz = s * 256;
    gemm_core<32>(A + kz, 512, B + (size_t)kz * 512, 512, 256, m0, n0, acc);
    int tid = threadIdx.x;
    int tx = tid & 15, ty = tid >> 4;
    float* out = part + (size_t)blockIdx.z * (512 * 512);
#pragma unroll
    for (int i = 0; i < 2; i++)
#pragma unroll
        for (int j = 0; j < 4; j++)
            out[(size_t)(m0 + ty * 2 + i) * 512 + n0 + tx * 4 + j] = acc[i][j];
}

// ---------------------------------------------------------------------------
// Split-K reduce + epilogue (bias -> act -> scale -> res)
// ---------------------------------------------------------------------------
__global__ __launch_bounds__(256) void k_reduce(const float* __restrict__ part, long mn, int S,
                                                const float* __restrict__ bias, unsigned bmask,
                                                const float* __restrict__ res,
                                                const float* __restrict__ scale,
                                                float* __restrict__ C, int N, int act) {
    long idx = ((long)blockIdx.x * 256 + threadIdx.x) * 4;
    if (idx >= mn) return;
    float4 v = *(const float4*)(part + idx);
    for (int s2 = 1; s2 < S; s2++) {
        float4 u = *(const float4*)(part + (size_t)s2 * mn + idx);
        v.x += u.x; v.y += u.y; v.z += u.z; v.w += u.w;
    }
    int col = (int)(idx % N);
    float vv[4] = {v.x, v.y, v.z, v.w};
#pragma unroll
    for (int j = 0; j < 4; j++) {
        float t = vv[j];
        int c = col + j;
        if (bias) t += bias[c & bmask];
        t = apply_act(t, act);
        if (scale) t *= scale[c];
        if (res) t += res[idx + j];
        vv[j] = t;
    }
    *(float4*)(C + idx) = make_float4(vv[0], vv[1], vv[2], vv[3]);
}

__global__ __launch_bounds__(256) void k_reduce_qkv(const float* __restrict__ part,
                                                    float* __restrict__ q,
                                                    float* __restrict__ k,
                                                    float* __restrict__ v) {
    const long mn = 262144;
    int w = blockIdx.y;
    long idx = ((long)blockIdx.x * 256 + threadIdx.x) * 4;
    float4 a = *(const float4*)(part + (size_t)(2 * w) * mn + idx);
    float4 b = *(const float4*)(part + (size_t)(2 * w + 1) * mn + idx);
    float* C = w == 0 ? q : (w == 1 ? k : v);
    *(float4*)(C + idx) = make_float4(a.x + b.x, a.y + b.y, a.z + b.z, a.w + b.w);
}

// ---------------------------------------------------------------------------
// RMSNorm rows of x[M,N]
// ---------------------------------------------------------------------------
__global__ __launch_bounds__(256) void k_rms(const float* __restrict__ x,
                                             const float* __restrict__ g,
                                             float* __restrict__ y, int N) {
    int row = blockIdx.x;
    const float* xr = x + (size_t)row * N;
    int tid = threadIdx.x;
    float s = 0.f;
    for (int i = tid; i < N; i += 256) { float v = xr[i]; s += v * v; }
#pragma unroll
    for (int off = 32; off; off >>= 1) s += __shfl_xor(s, off);
    __shared__ float red[4];
    if ((tid & 63) == 0) red[tid >> 6] = s;
    __syncthreads();
    s = red[0] + red[1] + red[2] + red[3];
    float r = 1.0f / sqrtf(s / (float)N + 1e-6f);
    for (int i = tid; i < N; i += 256) y[(size_t)row * N + i] = xr[i] * r * g[i];
}

// ---------------------------------------------------------------------------
// Fused qk-norm + RoPE (cos/sin from precomputed table)
// ---------------------------------------------------------------------------
__global__ void k_qkrope2(float* __restrict__ q, float* __restrict__ k,
                          const float* __restrict__ gq, const float* __restrict__ gk,
                          const float* __restrict__ tab) {
    int bid = blockIdx.x;
    int t = bid >> 3, h = bid & 7;
    int d = threadIdx.x;
    float* p = (blockIdx.y == 0 ? q : k) + (size_t)t * D_DIM + h * HD;
    const float* g = blockIdx.y == 0 ? gq : gk;
    float val = p[d];
    float s = val * val;
#pragma unroll
    for (int off = 32; off; off >>= 1) s += __shfl_xor(s, off);
    float r = 1.0f / sqrtf(s * (1.0f / 64.0f) + 1e-6f);
    float y = val * r * g[d];
    int dm = d & 31;
    float c = tab[t * 32 + dm];
    float sn = tab[16384 + t * 32 + dm];
    float partner = __shfl_xor(y, 32);
    float out = (d < 32) ? (y * c - partner * sn) : (y * c + partner * sn);
    p[d] = out;
}

// ---------------------------------------------------------------------------
// MFMA flash attention (fp16x3 hi/lo = ~fp32 precision).
// Grid: 256 blocks = (h = bid>>5) x (qt = bid&31, 16 q-rows). 128 threads =
// 2 waves; wave s handles key-chunks kt = s, s+2, ... (32 keys each),
// online softmax per wave, partials merged via LDS.
// S-tile: A=K (row=key), B=Q (col=qrow=lane&15) -> stats lane-local per fr.
// PV: A=P[qrow][key] (via LDS transpose), B=V (direct global reads).
// ---------------------------------------------------------------------------
__global__ __launch_bounds__(128) void k_attn_mf(const float* __restrict__ q,
                                                 const float* __restrict__ k,
                                                 const float* __restrict__ v,
                                                 float* __restrict__ o) {
    __shared__ _Float16 Ph[2][16][32];
    __shared__ _Float16 Pl[2][16][32];
    __shared__ float mM[16], lM[16], OM[16][64];
    int h = blockIdx.x >> 5, qt = blockIdx.x & 31;
    int qr0 = qt << 4;
    int tid = threadIdx.x;
    int s = tid >> 6, lane = tid & 63;
    int fr = lane & 15, g = lane >> 4;
    int hoff = h * 64;

    // Q fragments, scale 0.125 folded in (exact pow2)
    f16x8 qh[2], ql[2];
    {
        const float* qp = q + (size_t)(qr0 + fr) * 512 + hoff + g * 8;
#pragma unroll
        for (int c = 0; c < 2; ++c) {
            float4 v0 = *(const float4*)(qp + c * 32);
            float4 v1 = *(const float4*)(qp + c * 32 + 4);
            float vv[8] = {v0.x, v0.y, v0.z, v0.w, v1.x, v1.y, v1.z, v1.w};
#pragma unroll
            for (int j = 0; j < 8; ++j) {
                float x = vv[j] * 0.125f;
                _Float16 hh = (_Float16)x;
                qh[c][j] = hh;
                ql[c][j] = (_Float16)(x - (float)hh);
            }
        }
    }

    float m_run = -3.4e38f, l_run = 0.f;
    f32x4 accO[4];
#pragma unroll
    for (int dt = 0; dt < 4; ++dt)
#pragma unroll
        for (int r = 0; r < 4; ++r) accO[dt][r] = 0.f;

    int nkt = (qr0 + 47) >> 5;
    for (int kt = s; kt < nkt; kt += 2) {
        int c0 = kt << 5;
        // ---- S = K·Q^T (3-mfma hi/lo), 2 key-tiles of 16 ----
        float sv[2][4];
        float mx = -3.4e38f;
#pragma unroll
        for (int t2 = 0; t2 < 2; ++t2) {
            const float* kp = k + (size_t)(c0 + t2 * 16 + fr) * 512 + hoff + g * 8;
            f16x8 kh[2], kl[2];
#pragma unroll
            for (int c = 0; c < 2; ++c) {
                float4 v0 = *(const float4*)(kp + c * 32);
                float4 v1 = *(const float4*)(kp + c * 32 + 4);
                float vv[8] = {v0.x, v0.y, v0.z, v0.w, v1.x, v1.y, v1.z, v1.w};
#pragma unroll
                for (int j = 0; j < 8; ++j) {
                    _Float16 hh = (_Float16)vv[j];
                    kh[c][j] = hh;
                    kl[c][j] = (_Float16)(vv[j] - (float)hh);
                }
            }
            f32x4 a;
#pragma unroll
            for (int r = 0; r < 4; ++r) a[r] = 0.f;
#pragma unroll
            for (int c = 0; c < 2; ++c) {
                a = __builtin_amdgcn_mfma_f32_16x16x32_f16(kh[c], qh[c], a, 0, 0, 0);
                a = __builtin_amdgcn_mfma_f32_16x16x32_f16(kh[c], ql[c], a, 0, 0, 0);
                a = __builtin_amdgcn_mfma_f32_16x16x32_f16(kl[c], qh[c], a, 0, 0, 0);
            }
            // causal mask: D[row=key=c0+t2*16+g*4+r][col=qrow=qr0+fr]
#pragma unroll
            for (int r = 0; r < 4; ++r) {
                int key = c0 + t2 * 16 + g * 4 + r;
                float x = (key <= qr0 + fr) ? a[r] : -3.4e38f;
                sv[t2][r] = x;
                mx = fmaxf(mx, x);
            }
        }
        mx = fmaxf(mx, __shfl_xor(mx, 16));
        mx = fmaxf(mx, __shfl_xor(mx, 32));
        float m_new = fmaxf(m_run, mx);
        float alpha = __expf(m_run - m_new);
        l_run *= alpha;
        // O-rescale (alpha per qrow=g*4+r, fetched from lanes 0..15)
        float ar[4];
#pragma unroll
        for (int r = 0; r < 4; ++r) ar[r] = __shfl(alpha, g * 4 + r);
#pragma unroll
        for (int dt = 0; dt < 4; ++dt)
#pragma unroll
            for (int r = 0; r < 4; ++r) accO[dt][r] *= ar[r];
        // P = exp(s - m_new); pack hi/lo to LDS [qrow][key]
        float psum = 0.f;
#pragma unroll
        for (int t2 = 0; t2 < 2; ++t2) {
            f16x4 ph4, pl4;
#pragma unroll
            for (int r = 0; r < 4; ++r) {
                float p = __expf(sv[t2][r] - m_new);
                psum += p;
                _Float16 hh = (_Float16)p;
                ph4[r] = hh;
                pl4[r] = (_Float16)(p - (float)hh);
            }
            *(f16x4*)(&Ph[s][fr][t2 * 16 + g * 4]) = ph4;
            *(f16x4*)(&Pl[s][fr][t2 * 16 + g * 4]) = pl4;
        }
        psum += __shfl_xor(psum, 16);
        psum += __shfl_xor(psum, 32);
        l_run += psum;
        m_run = m_new;
        // ---- PV: A=P[qrow=fr][key=g*8+j], B=V[key][d=dt*16+fr] ----
        f16x8 pah = *(const f16x8*)(&Ph[s][fr][g * 8]);
        f16x8 pal = *(const f16x8*)(&Pl[s][fr][g * 8]);
#pragma unroll
        for (int dt = 0; dt < 4; ++dt) {
            const float* vp = v + (size_t)(c0 + g * 8) * 512 + hoff + dt * 16 + fr;
            f16x8 bh, bl;
#pragma unroll
            for (int j = 0; j < 8; ++j) {
                float x = vp[(size_t)j * 512];
                _Float16 hh = (_Float16)x;
                bh[j] = hh;
                bl[j] = (_Float16)(x - (float)hh);
            }
            accO[dt] = __builtin_amdgcn_mfma_f32_16x16x32_f16(pah, bh, accO[dt], 0, 0, 0);
            accO[dt] = __builtin_amdgcn_mfma_f32_16x16x32_f16(pah, bl, accO[dt], 0, 0, 0);
            accO[dt] = __builtin_amdgcn_mfma_f32_16x16x32_f16(pal, bh, accO[dt], 0, 0, 0);
        }
    }
    // ---- merge the two waves' partials ----
    if (s == 1) {
        if (g == 0) { mM[fr] = m_run; lM[fr] = l_run; }
#pragma unroll
        for (int dt = 0; dt < 4; ++dt)
#pragma unroll
            for (int r = 0; r < 4; ++r)
                OM[g * 4 + r][dt * 16 + fr] = accO[dt][r];
    }
    __syncthreads();
    if (s == 0) {
        float m1 = mM[fr], l1 = lM[fr];
        float mf = fmaxf(m_run, m1);
        float a0 = __expf(m_run - mf), a1 = __expf(m1 - mf);
        float lf = l_run * a0 + l1 * a1;
        float inv = 1.0f / lf;
        float a0r[4], a1r[4], invr[4];
#pragma unroll
        for (int r = 0; r < 4; ++r) {
            a0r[r] = __shfl(a0, g * 4 + r);
            a1r[r] = __shfl(a1, g * 4 + r);
            invr[r] = __shfl(inv, g * 4 + r);
        }
#pragma unroll
        for (int dt = 0; dt < 4; ++dt)
#pragma unroll
            for (int r = 0; r < 4; ++r) {
                float ov = (accO[dt][r] * a0r[r] + OM[g * 4 + r][dt * 16 + fr] * a1r[r]) * invr[r];
                o[(size_t)(qr0 + g * 4 + r) * 512 + hoff + dt * 16 + fr] = ov;
            }
    }
}

// ---------------------------------------------------------------------------
// Final conv: Cin=32 -> 1, K=7 SAME, clip
// ---------------------------------------------------------------------------
__global__ __launch_bounds__(256) void k_conv_fin(const float* __restrict__ x,
                                                  const float* __restrict__ w,
                                                  const float* __restrict__ b,
                                                  float* __restrict__ y, int n) {
    __shared__ float xs[262 * 33];
    __shared__ float wsm[224];
    int tid = threadIdx.x;
    int o0 = blockIdx.x * 256;
    for (int i = tid; i < 262 * 32; i += 256) {
        int r = i >> 5, c = i & 31;
        int t = o0 - 3 + r;
        xs[r * 33 + c] = (t >= 0 && t < n) ? x[(size_t)t * 32 + c] : 0.f;
    }
    if (tid < 224) wsm[tid] = w[tid];
    __syncthreads();
    float acc = b[0];
#pragma unroll
    for (int kk = 0; kk < 7; kk++)
#pragma unroll
        for (int ci = 0; ci < 32; ci++)
            acc += xs[(tid + kk) * 33 + ci] * wsm[kk * 32 + ci];
    y[o0 + tid] = fminf(fmaxf(acc, -1.f), 1.f);
}

// ---------------------------------------------------------------------------
// Host helpers
// ---------------------------------------------------------------------------
static inline void gemmS64(hipStream_t st, const float* A, int lda, const float* B,
                           const float* bias, unsigned bmask, const float* res,
                           const float* scale, float* C, float* part,
                           int M, int N, int K, int S, int act) {
    long mn = (long)M * N;
    if (S > 1) {
        k_gemm2<64><<<dim3(M / 64, N / 64, S), 256, 0, st>>>(
            A, lda, B, nullptr, 0, nullptr, nullptr, nullptr, part, mn, N, K / S, 0);
        k_reduce<<<dim3((int)(mn / 1024)), 256, 0, st>>>(
            part, mn, S, bias, bmask, res, scale, C, N, act);
    } else {
        k_gemm2<64><<<dim3(M / 64, N / 64, 1), 256, 0, st>>>(
            A, lda, B, bias, bmask, res, scale, C, nullptr, mn, N, K, act);
    }
}
static inline void gemmS32(hipStream_t st, const float* A, int lda, const float* B,
                           const float* bias, unsigned bmask, const float* res,
                           const float* scale, float* C, float* part,
                           int M, int N, int K, int S, int act) {
    long mn = (long)M * N;
    if (S > 1) {
        k_gemm2<32><<<dim3(M / 32, N / 64, S), 256, 0, st>>>(
            A, lda, B, nullptr, 0, nullptr, nullptr, nullptr, part, mn, N, K / S, 0);
        k_reduce<<<dim3((int)(mn / 1024)), 256, 0, st>>>(
            part, mn, S, bias, bmask, res, scale, C, N, act);
    } else {
        k_gemm2<32><<<dim3(M / 32, N / 64, 1), 256, 0, st>>>(
            A, lda, B, bias, bmask, res, scale, C, nullptr, mn, N, K, act);
    }
}

extern "C" void kernel_launch(void* const* d_in, const int* in_sizes, int n_in,
                              void* d_out, int out_size, void* d_ws, size_t ws_size,
                              hipStream_t stream) {
    int i = 0;
    const int*   codes     = (const int*)  d_in[i++];
    const float* emb_first = (const float*)d_in[i++];
    const float* pf_w      = (const float*)d_in[i++];
    const float* pf_b      = (const float*)d_in[i++];
    const float* fo_w      = (const float*)d_in[i++];
    const float* fo_b      = (const float*)d_in[i++];
    const float* emb_rest  = (const float*)d_in[i++];
    const float* pr_w      = (const float*)d_in[i++];
    const float* pr_b      = (const float*)d_in[i++];
    const float* ro_w      = (const float*)d_in[i++];
    const float* ro_b      = (const float*)d_in[i++];
    const float* pre_w     = (const float*)d_in[i++];
    const float* pre_b     = (const float*)d_in[i++];
    const float* in_w      = (const float*)d_in[i++];
    const float* in_b      = (const float*)d_in[i++];
    const float* ln1       = (const float*)d_in[i++];
    const float* qw        = (const float*)d_in[i++];
    const float* kw        = (const float*)d_in[i++];
    const float* vw        = (const float*)d_in[i++];
    const float* ow        = (const float*)d_in[i++];
    const float* qn        = (const float*)d_in[i++];
    const float* kn        = (const float*)d_in[i++];
    const float* ls_a      = (const float*)d_in[i++];
    const float* ln2       = (const float*)d_in[i++];
    const float* w1        = (const float*)d_in[i++];
    const float* w2        = (const float*)d_in[i++];
    const float* ls_m      = (const float*)d_in[i++];
    const float* fn_w      = (const float*)d_in[i++];
    const float* out_w     = (const float*)d_in[i++];
    const float* out_b     = (const float*)d_in[i++];
    const float* up_w      = (const float*)d_in[i++];
    const float* up_b      = (const float*)d_in[i++];
    const float* dec0_w    = (const float*)d_in[i++];
    const float* dec0_b    = (const float*)d_in[i++];
    const float* dw1       = (const float*)d_in[i++];
    const float* db1       = (const float*)d_in[i++];
    const float* dw2       = (const float*)d_in[i++];
    const float* db2       = (const float*)d_in[i++];
    const float* dw3       = (const float*)d_in[i++];
    const float* db3       = (const float*)d_in[i++];
    const float* dw4       = (const float*)d_in[i++];
    const float* db4       = (const float*)d_in[i++];
    const float* fin_w     = (const float*)d_in[i++];
    const float* fin_b     = (const float*)d_in[i++];

    float* ws = (float*)d_ws;
    float* outp = (float*)d_out;

    float* qf_pre   = ws + WS_QFPRE;
    float* G        = ws + WS_G;
    float* qf       = ws + WS_QF;
    float* tA       = ws + WS_TA;
    float* hidden   = ws + WS_HID;
    float* conv_out = ws + WS_CONV;
    float* h        = ws + WS_H;
    float* x        = ws + WS_X;
    float* qb       = ws + WS_QB;
    float* kb       = ws + WS_KB;
    float* vb       = ws + WS_VB;
    float* attnb    = ws + WS_ATT;
    float* ff       = ws + WS_FF;
    float* bias_sum = ws + WS_BSUM;
    float* houtp    = ws + WS_HOUT;
    float* up_out   = ws + WS_UP;
    float* dec0_out = ws + WS_DEC0;
    float* t1       = ws + WS_T1;
    float* t2       = ws + WS_T2;
    float* t3       = ws + WS_T3;
    float* t4       = ws + WS_T4;
    float* part     = ws + WS_PART;
    float* ropetab  = ws + WS_ROPE;

    // f16 hi/lo transposed weight planes (exact-fit aliases of old W2 regions)
    _Float16* BTup_h = (_Float16*)(ws + WS_W2UP);   _Float16* BTup_l = BTup_h + 2048 * 3072;
    _Float16* BTd1_h = (_Float16*)(ws + WS_W2D1);   _Float16* BTd1_l = BTd1_h + 2048 * 1536;
    _Float16* BTd2_h = (_Float16*)(ws + WS_W2D2);   _Float16* BTd2_l = BTd2_h + 768 * 768;
    _Float16* BTd3_h = (_Float16*)(ws + WS_W2D3);   _Float16* BTd3_l = BTd3_h + 320 * 384;
    _Float16* BTd4_h = (_Float16*)(ws + WS_W2D4);   _Float16* BTd4_l = BTd4_h + 128 * 192;
    _Float16* BTd0_h = (_Float16*)(ws + WS_DEC0B16);_Float16* BTd0_l = BTd0_h + 512 * 7168;
    _Float16* BTpr_h = (_Float16*)(ws + WS_BTPR);   _Float16* BTpr_l = BTpr_h + 1024 * 3840;

    // --- prep ---
    k_zero_guards<<<13, 256, 0, stream>>>(ws);
    k_rope_tab<<<64, 256, 0, stream>>>(ropetab);
    k_wt16<<<dim3(32, 24), 256, 0, stream>>>(up_w, BTup_h, BTup_l, 1024, 1024, 2, 2);
    k_wt16<<<dim3(32, 12), 256, 0, stream>>>(dw1, BTd1_h, BTd1_l, 512, 256, 8, 11);
    k_wt16<<<dim3(12, 6), 256, 0, stream>>>(dw2, BTd2_h, BTd2_l, 256, 128, 6, 8);
    k_wt16<<<dim3(5, 3), 256, 0, stream>>>(dw3, BTd3_h, BTd3_l, 128, 64, 5, 7);
    k_wt16<<<dim3(2, 2), 256, 0, stream>>>(dw4, BTd4_h, BTd4_l, 64, 32, 4, 5);
    k_bt16<<<dim3(8, 56), 256, 0, stream>>>(dec0_w, BTd0_h, BTd0_l, 7168, 512);
    k_bt16<<<dim3(16, 30), 256, 0, stream>>>(pr_w, BTpr_h, BTpr_l, 3840, 1024);

    // --- RVQ decode ---
    k_gather<<<8192, 256, 0, stream>>>(codes, emb_first, emb_rest, qf_pre, G);
    k_bias_sum<<<4, 256, 0, stream>>>(pr_b, bias_sum);
    gemmS64(stream, qf_pre, 256, pf_w, pf_b, ~0u, nullptr, nullptr, tA, part, 512, 1024, 256, 2, 0);
    gemmS64(stream, tA, 1024, fo_w, fo_b, ~0u, nullptr, nullptr, qf, part, 512, 1024, 1024, 4, 0);
    // pr_w GEMM (K=3840) on the MFMA path, split-K=4
    k_gemm16<<<dim3(4, 16, 4), 256, 0, stream>>>(G, 3840, BTpr_h, BTpr_l, 3840,
            nullptr, 0, nullptr, part, 524288L, 1024, 960, 0);
    k_reduce<<<512, 256, 0, stream>>>(part, 524288L, 4, bias_sum, ~0u, nullptr, nullptr,
            tA, 1024, 0);
    gemmS64(stream, tA, 1024, ro_w, ro_b, ~0u, qf, nullptr, hidden, part, 512, 1024, 1024, 4, 0);

    // --- causal pre-conv (k=3) via windowed GEMM ---
    gemmS64(stream, hidden - 2048, 1024, pre_w, pre_b, ~0u, nullptr, nullptr,
            conv_out, part, 512, 1024, 3072, 8, 0);

    // --- transformer input proj ---
    gemmS32(stream, conv_out, 1024, in_w, in_b, ~0u, nullptr, nullptr, h, part, 512, 512, 1024, 4, 0);

    // --- 8 transformer layers ---
    for (int l = 0; l < NL; l++) {
        const float* qw_l = qw + (size_t)l * D_DIM * D_DIM;
        const float* kw_l = kw + (size_t)l * D_DIM * D_DIM;
        const float* vw_l = vw + (size_t)l * D_DIM * D_DIM;
        const float* ow_l = ow + (size_t)l * D_DIM * D_DIM;
        const float* w1_l = w1 + (size_t)l * D_DIM * FF_D;
        const float* w2_l = w2 + (size_t)l * FF_D * D_DIM;

        k_rms<<<512, 256, 0, stream>>>(h, ln1 + l * D_DIM, x, D_DIM);
        k_qkv<<<dim3(16, 8, 6), 256, 0, stream>>>(x, qw_l, kw_l, vw_l, part);
        k_reduce_qkv<<<dim3(256, 3), 256, 0, stream>>>(part, qb, kb, vb);
        k_qkrope2<<<dim3(T_LEN * NH, 2), 64, 0, stream>>>(qb, kb, qn + l * HD, kn + l * HD, ropetab);
        k_attn_mf<<<256, 128, 0, stream>>>(qb, kb, vb, attnb);
        gemmS32(stream, attnb, 512, ow_l, nullptr, 0, h, ls_a + l * D_DIM, h, part,
                512, 512, 512, 2, 0);
        k_rms<<<512, 256, 0, stream>>>(h, ln2 + l * D_DIM, x, D_DIM);
        gemmS64(stream, x, 512, w1_l, nullptr, 0, nullptr, nullptr, ff, part,
                512, 2048, 512, 2, 1);
        gemmS32(stream, ff, 2048, w2_l, nullptr, 0, h, ls_m + l * D_DIM, h, part,
                512, 512, 2048, 8, 0);
    }

    // --- final norm + out proj ---
    k_rms<<<512, 256, 0, stream>>>(h, fn_w, x, D_DIM);
    gemmS64(stream, x, 512, out_w, out_b, ~0u, nullptr, nullptr, houtp, part, 512, 1024, 512, 4, 0);

    // --- upsample x2 convT as GEMM (fp16x3 MFMA), elu; split-K=2 ---
    k_gemm16<<<dim3(4, 32, 2), 256, 0, stream>>>(houtp - 1024, 1024, BTup_h, BTup_l, 3072,
            nullptr, 0, nullptr, part, 1048576L, 2048, 1536, 0);
    k_reduce<<<1024, 256, 0, stream>>>(part, 1048576L, 2, up_b, 1023u, nullptr, nullptr,
            up_out, 2048, 2);

    // --- dec0 conv k=7 SAME via windowed GEMM (fp16x3 MFMA), elu; split-K=4 ---
    k_gemm16<<<dim3(8, 8, 4), 256, 0, stream>>>(up_out - 3072, 1024, BTd0_h, BTd0_l, 7168,
            nullptr, 0, nullptr, part, 524288L, 512, 1792, 0);
    k_reduce<<<512, 256, 0, stream>>>(part, 524288L, 4, dec0_b, ~0u, nullptr, nullptr,
            dec0_out, 512, 2);

    // --- SEANet convT chain as fp16x3 MFMA GEMMs, elu ---
    k_gemm16<<<dim3(8, 32, 1), 256, 0, stream>>>(dec0_out - 512, 512, BTd1_h, BTd1_l, 1536,
            db1, 255u, t1, nullptr, 0L, 2048, 1536, 2);
    k_gemm16<<<dim3(64, 12, 1), 256, 0, stream>>>(t1 - 256, 256, BTd2_h, BTd2_l, 768,
            db2, 127u, t2, nullptr, 0L, 768, 768, 2);
    k_gemm16<<<dim3(384, 5, 1), 256, 0, stream>>>(t2 - 128, 128, BTd3_h, BTd3_l, 384,
            db3, 63u, t3, nullptr, 0L, 320, 384, 2);
    k_gemm16<<<dim3(1920, 2, 1), 256, 0, stream>>>(t3 - 64, 64, BTd4_h, BTd4_l, 192,
            db4, 31u, t4, nullptr, 0L, 128, 192, 2);

    // --- final conv ---
    k_conv_fin<<<983040 / 256, 256, 0, stream>>>(t4, fin_w, fin_b, outp, 983040);
}

// Round 3
// 2006.264 us; speedup vs baseline: 1.6148x; 1.0134x over previous
//
#include <hip/hip_runtime.h>
#include <hip/hip_bf16.h>
#include <math.h>

#define T_LEN 512
#define LAT   1024
#define D_DIM 512
#define NH    8
#define HD    64
#define FF_D  2048
#define NL    8
#define NQ    16

typedef _Float16 f16x4 __attribute__((ext_vector_type(4)));
typedef _Float16 f16x8 __attribute__((ext_vector_type(8)));
typedef float    f32x4 __attribute__((ext_vector_type(4)));

// ---------------------------------------------------------------------------
// Workspace layout (float offsets)
// ---------------------------------------------------------------------------
#define WS_QFPRE    0
#define WS_G        131072
#define WS_QF       2097152
#define WS_TA       2621440
#define WS_HIDG     3145728            // 2048 guard floats before hidden
#define WS_HID      3147776
#define WS_CONV     3672064
#define WS_H        4196352
#define WS_X        4458496
#define WS_QB       4720640
#define WS_KB       4982784
#define WS_VB       5244928
#define WS_ATT      5507072
#define WS_FF       5769216
#define WS_BSUM     6817792
#define WS_HOUT     6819840            // guard 1024 at 6818816, post at 7344128
// f16 hi/lo plane buffers for the tail chain. Each buffer = hi plane || lo
// plane, each plane = [g guard rows | data rows | g guard rows] x C f16.
// Exact same float footprint as the old fp32 buffer incl guards.
//   up16:  C=1024 R=1024 g=3  base 7345152  (hi data 7346688, lo data 7874048)
//   dec16: C=512  R=1024 g=1  base 8399872  (hi 8400128, lo 8662784)
//   t1_16: C=256  R=8192 g=1  base 8925184  (hi 8925312, lo 9974144)
//   t2_16: C=128  R=49152 g=1 base 11022848 (hi 11022912, lo 14168768)
//   t3_16: C=64   R=245760 g=1 base 31457280 (hi 31457312, lo 39321696)
#define UP16H_D   7346688
#define UP16L_D   7874048
#define DEC16H_D  8400128
#define DEC16L_D  8662784
#define T1H_D     8925312
#define T1L_D     9974144
#define T2H_D     11022912
#define T2L_D     14168768
#define T3H_D     31457312
#define T3L_D     39321696
#define WS_W2UP     17314560           // 6291456 floats -> f16 hi/lo planes
#define WS_W2D1     23606016           // 3145728
#define WS_W2D2     26751744           // 589824
#define WS_W2D3     27341568           // 122880
#define WS_W2D4     47186048           // 24576 -> ends 47210624
#define WS_T4       0                  // aliases phase-A region (dead by then)
// dec0 transposed f16 weights: aliases t2 data region (dec0 consumes them
// before d2 writes t2). t2/t3 guards re-zeroed by k_zero2 after dec0.
#define WS_DEC0B16  11022976
// split-K partials: alias t3 data region (dead until d3 writes it)
#define WS_PART     31457344
// pr_w transposed f16 planes (consumed in RVQ, clobbered later by t3 planes)
#define WS_BTPR     35651712
// RoPE cos/sin table (last use before tail; clobbered by t3 lo plane)
#define WS_ROPE     39583872

// ---------------------------------------------------------------------------
// Guard zeroing (ws is poisoned before every launch).
// Prep list: fp32 guards + up16/dec16/t1 plane guards (never clobbered).
// ---------------------------------------------------------------------------
__global__ void k_zero_guards(float* __restrict__ ws) {
    const int offs[15] = {3145728, 6818816, 7344128,
                          7345152, 7870976, 7872512, 8398336,
                          8399872, 8662272, 8662528, 8924928,
                          8925184, 9973888, 9974016, 11022720};
    const int lens[15] = {2048, 1024, 1024,
                          1536, 1536, 1536, 1536,
                          256, 256, 256, 256,
                          128, 128, 128, 128};
    int r = blockIdx.x;
    for (int i = threadIdx.x; i < lens[r]; i += 256) ws[offs[r] + i] = 0.f;
}

// t2/t3 plane guards: zeroed after BTd0 (t2 region) and BTpr/part (t3 region)
// are dead -- launched right after the dec0 reduce.
__global__ void k_zero2(float* __restrict__ ws) {
    const int offs[8] = {11022848, 14168640, 14168704, 17314496,
                         31457280, 39321632, 39321664, 47186016};
    const int lens[8] = {64, 64, 64, 64, 32, 32, 32, 32};
    int r = blockIdx.x;
    for (int i = threadIdx.x; i < lens[r]; i += 256) ws[offs[r] + i] = 0.f;
}

// ---------------------------------------------------------------------------
// Gathers
// ---------------------------------------------------------------------------
__global__ __launch_bounds__(256) void k_gather(const int* __restrict__ codes,
                                                const float* __restrict__ emb_first,
                                                const float* __restrict__ emb_rest,
                                                float* __restrict__ qf_pre,
                                                float* __restrict__ G) {
    int idx = blockIdx.x * 256 + threadIdx.x;
    int c = idx & 255;
    int r = (idx >> 8) & 15;
    int t = idx >> 12;
    if (t >= T_LEN) return;
    if (r == 0) {
        int code = codes[t];
        qf_pre[t * 256 + c] = emb_first[code * 256 + c];
    } else {
        int n = r - 1;
        int code = codes[(n + 1) * T_LEN + t];
        G[t * 3840 + n * 256 + c] = emb_rest[(n * 2048 + code) * 256 + c];
    }
}

__global__ void k_bias_sum(const float* __restrict__ pr_b, float* __restrict__ out) {
    int d = blockIdx.x * 256 + threadIdx.x;
    if (d >= LAT) return;
    float s = 0.f;
    for (int n = 0; n < NQ - 1; n++) s += pr_b[n * LAT + d];
    out[d] = s;
}

// RoPE cos/sin table: tab[0..16383]=cos(t*inv(dm)), tab[16384..]=sin
__global__ void k_rope_tab(float* __restrict__ tab) {
    int idx = blockIdx.x * 256 + threadIdx.x;
    int t = idx >> 5, dm = idx & 31;
    double inv = pow(10000.0, -(double)dm / 32.0);
    double ang = (double)t * inv;
    tab[idx] = (float)cos(ang);
    tab[16384 + idx] = (float)sin(ang);
}

// ---------------------------------------------------------------------------
// convT weight transform -> TRANSPOSED f16 hi/lo planes [N=s*Cout][K3=3*Cin].
// ---------------------------------------------------------------------------
__global__ __launch_bounds__(256) void k_wt16(const float* __restrict__ w,
                                              _Float16* __restrict__ bth,
                                              _Float16* __restrict__ btl,
                                              int Cin, int Cout, int s, int pad_a) {
    int K3 = 3 * Cin;
    int col = blockIdx.x * 64 + (threadIdx.x & 63);
    int rk0 = blockIdx.y * 128 + (threadIdx.x >> 6) * 32;
    if (rk0 >= K3) return;
    int p = col / Cout, co = col - p * Cout;
    int kk0 = (pad_a - p) % s;
    if (kk0 < 0) kk0 += s;
    int cp = (p + kk0 - pad_a) / s;
    size_t ob = (size_t)col * K3 + rk0;
    for (int rb = 0; rb < 32; rb += 4) {
        f16x4 h, l;
#pragma unroll
        for (int j2 = 0; j2 < 4; ++j2) {
            int rowk = rk0 + rb + j2;
            int j = rowk / Cin, ci = rowk - j * Cin;
            int d = j - 1;
            float v = 0.f;
            if (d == cp) v = w[((size_t)kk0 * Cin + ci) * Cout + co];
            else if (d == cp + 1) v = w[((size_t)(kk0 + s) * Cin + ci) * Cout + co];
            _Float16 hh = (_Float16)v;
            h[j2] = hh;
            l[j2] = (_Float16)(v - (float)hh);
        }
        *(f16x4*)(bth + ob + rb) = h;
        *(f16x4*)(btl + ob + rb) = l;
    }
}

// Plain transpose+split: [K][N] fp32 -> [N][K] f16 hi/lo
__global__ __launch_bounds__(256) void k_bt16(const float* __restrict__ w,
                                              _Float16* __restrict__ bth,
                                              _Float16* __restrict__ btl,
                                              int K, int N) {
    int col = blockIdx.x * 64 + (threadIdx.x & 63);
    int rk0 = blockIdx.y * 128 + (threadIdx.x >> 6) * 32;
    size_t ob = (size_t)col * K + rk0;
    for (int rb = 0; rb < 32; rb += 4) {
        f16x4 h, l;
#pragma unroll
        for (int j2 = 0; j2 < 4; ++j2) {
            float v = w[(size_t)(rk0 + rb + j2) * N + col];
            _Float16 hh = (_Float16)v;
            h[j2] = hh;
            l[j2] = (_Float16)(v - (float)hh);
        }
        *(f16x4*)(bth + ob + rb) = h;
        *(f16x4*)(btl + ob + rb) = l;
    }
}

__device__ __forceinline__ float apply_act(float v, int act) {
    if (act == 1) return 0.5f * v * (1.0f + erff(v * 0.70710678118654752440f));
    if (act == 2) return v > 0.f ? v : expm1f(v);
    return v;
}

// ---------------------------------------------------------------------------
// fp16x3 MFMA GEMM, fp32 A split on the fly (used where A is fp32).
// Tile 128x64, BK=64, 256 threads = 4 waves (2M x 2N), swizzled LDS.
// ---------------------------------------------------------------------------
__global__ __launch_bounds__(256) void k_gemm16(const float* __restrict__ A, int lda,
                                                const _Float16* __restrict__ BTh,
                                                const _Float16* __restrict__ BTl, int ldb,
                                                const float* __restrict__ bias, unsigned bmask,
                                                float* __restrict__ C,
                                                float* __restrict__ part, long mn,
                                                int N, int klen, int act) {
    __shared__ _Float16 Ash[128 * 64];
    __shared__ _Float16 Asl[128 * 64];
    __shared__ _Float16 Bsh[64 * 64];
    __shared__ _Float16 Bsl[64 * 64];
    int tid = threadIdx.x;
    int m0 = blockIdx.x * 128, n0 = blockIdx.y * 64;
    int kz = blockIdx.z * klen;
    const float* Ab = A + kz;
    int lane = tid & 63, wv = tid >> 6;
    int wr = wv >> 1, wc = wv & 1;
    int fr = lane & 15, g = lane >> 4;

    f32x4 acc[4][2];
#pragma unroll
    for (int m = 0; m < 4; ++m)
#pragma unroll
        for (int n = 0; n < 2; ++n)
#pragma unroll
            for (int r = 0; r < 4; ++r) acc[m][n][r] = 0.f;

    int nk = klen >> 6;
    for (int t = 0; t < nk; ++t) {
        int k0 = t << 6;
#pragma unroll
        for (int i2 = 0; i2 < 8; ++i2) {
            int c = tid + 256 * i2;
            int row = c >> 4, kc = c & 15;
            float4 v = *(const float4*)(Ab + (size_t)(m0 + row) * lda + k0 + (kc << 2));
            f16x4 h, l;
            float vv[4] = {v.x, v.y, v.z, v.w};
#pragma unroll
            for (int j = 0; j < 4; ++j) {
                _Float16 hh = (_Float16)vv[j];
                h[j] = hh;
                l[j] = (_Float16)(vv[j] - (float)hh);
            }
            int off = row * 64 + (((kc >> 1) ^ (row & 7)) << 3) + ((kc & 1) << 2);
            *(f16x4*)(Ash + off) = h;
            *(f16x4*)(Asl + off) = l;
        }
#pragma unroll
        for (int i2 = 0; i2 < 2; ++i2) {
            int c = tid + 256 * i2;
            int col = c >> 3, s = c & 7;
            size_t goff = (size_t)(n0 + col) * ldb + kz + k0 + (s << 3);
            f16x8 hv = *(const f16x8*)(BTh + goff);
            f16x8 lv = *(const f16x8*)(BTl + goff);
            int off = col * 64 + ((s ^ (col & 7)) << 3);
            *(f16x8*)(Bsh + off) = hv;
            *(f16x8*)(Bsl + off) = lv;
        }
        __syncthreads();
#pragma unroll
        for (int kk = 0; kk < 2; ++kk) {
            f16x8 ah[4], al[4], bh[2], bl[2];
#pragma unroll
            for (int m = 0; m < 4; ++m) {
                int row = wr * 64 + m * 16 + fr;
                int off = row * 64 + ((((kk << 2) + g) ^ (row & 7)) << 3);
                ah[m] = *(const f16x8*)(Ash + off);
                al[m] = *(const f16x8*)(Asl + off);
            }
#pragma unroll
            for (int n = 0; n < 2; ++n) {
                int col = wc * 32 + n * 16 + fr;
                int off = col * 64 + ((((kk << 2) + g) ^ (col & 7)) << 3);
                bh[n] = *(const f16x8*)(Bsh + off);
                bl[n] = *(const f16x8*)(Bsl + off);
            }
#pragma unroll
            for (int m = 0; m < 4; ++m)
#pragma unroll
                for (int n = 0; n < 2; ++n) {
                    acc[m][n] = __builtin_amdgcn_mfma_f32_16x16x32_f16(ah[m], bh[n], acc[m][n], 0, 0, 0);
                    acc[m][n] = __builtin_amdgcn_mfma_f32_16x16x32_f16(ah[m], bl[n], acc[m][n], 0, 0, 0);
                    acc[m][n] = __builtin_amdgcn_mfma_f32_16x16x32_f16(al[m], bh[n], acc[m][n], 0, 0, 0);
                }
        }
        __syncthreads();
    }
    if (part) {
        float* op = part + (size_t)blockIdx.z * mn;
#pragma unroll
        for (int m = 0; m < 4; ++m) {
            int row = m0 + wr * 64 + m * 16 + (g << 2);
#pragma unroll
            for (int n = 0; n < 2; ++n) {
                int col = n0 + wc * 32 + n * 16 + fr;
#pragma unroll
                for (int r = 0; r < 4; ++r)
                    op[(size_t)(row + r) * N + col] = acc[m][n][r];
            }
        }
    } else {
#pragma unroll
        for (int m = 0; m < 4; ++m) {
            int row = m0 + wr * 64 + m * 16 + (g << 2);
#pragma unroll
            for (int n = 0; n < 2; ++n) {
                int col = n0 + wc * 32 + n * 16 + fr;
                float bv = bias ? bias[col & bmask] : 0.f;
#pragma unroll
                for (int r = 0; r < 4; ++r) {
                    float v = acc[m][n][r] + bv;
                    v = apply_act(v, act);
                    C[(size_t)(row + r) * N + col] = v;
                }
            }
        }
    }
}

// ---------------------------------------------------------------------------
// fp16x3 MFMA GEMM, A from PRE-SPLIT f16 hi/lo planes (no cvt in staging).
// NT=4: tile 128x128 (4 waves 2x2, each 64x64 = 4x4 frags), LDS 64KB.
// NT=2: tile 128x64  (wave 64x32 = 4x2 frags), LDS 48KB.
// Output: raw partials (part), f16 hi/lo planes (Ch/Cl), or fp32 (C).
// ---------------------------------------------------------------------------
template <int NT>
__global__ __launch_bounds__(256) void k_gemm16h(
        const _Float16* __restrict__ Ah, const _Float16* __restrict__ Al, int lda,
        const _Float16* __restrict__ BTh, const _Float16* __restrict__ BTl, int ldb,
        const float* __restrict__ bias, unsigned bmask,
        float* __restrict__ C, _Float16* __restrict__ Ch, _Float16* __restrict__ Cl,
        float* __restrict__ part, long mn, int N, int klen, int act) {
    constexpr int BN = NT * 32;
    __shared__ _Float16 Ash[128 * 64];
    __shared__ _Float16 Asl[128 * 64];
    __shared__ _Float16 Bsh[BN * 64];
    __shared__ _Float16 Bsl[BN * 64];
    int tid = threadIdx.x;
    int m0 = blockIdx.x * 128, n0 = blockIdx.y * BN;
    int kz = blockIdx.z * klen;
    int lane = tid & 63, wv = tid >> 6;
    int wr = wv >> 1, wc = wv & 1;
    int fr = lane & 15, g = lane >> 4;

    f32x4 acc[4][NT];
#pragma unroll
    for (int m = 0; m < 4; ++m)
#pragma unroll
        for (int n = 0; n < NT; ++n)
#pragma unroll
            for (int r = 0; r < 4; ++r) acc[m][n][r] = 0.f;

    int nk = klen >> 6;
    for (int t = 0; t < nk; ++t) {
        int k0 = kz + (t << 6);
        // stage A: pure copies, swizzled
#pragma unroll
        for (int i2 = 0; i2 < 4; ++i2) {
            int c = tid + 256 * i2;
            int row = c >> 3, s = c & 7;
            size_t go = (size_t)(m0 + row) * lda + k0 + (s << 3);
            f16x8 hv = *(const f16x8*)(Ah + go);
            f16x8 lv = *(const f16x8*)(Al + go);
            int off = row * 64 + ((s ^ (row & 7)) << 3);
            *(f16x8*)(Ash + off) = hv;
            *(f16x8*)(Asl + off) = lv;
        }
#pragma unroll
        for (int i2 = 0; i2 < BN / 32; ++i2) {
            int c = tid + 256 * i2;
            int col = c >> 3, s = c & 7;
            size_t go = (size_t)(n0 + col) * ldb + k0 + (s << 3);
            f16x8 hv = *(const f16x8*)(BTh + go);
            f16x8 lv = *(const f16x8*)(BTl + go);
            int off = col * 64 + ((s ^ (col & 7)) << 3);
            *(f16x8*)(Bsh + off) = hv;
            *(f16x8*)(Bsl + off) = lv;
        }
        __syncthreads();
#pragma unroll
        for (int kk = 0; kk < 2; ++kk) {
            f16x8 ah[4], al4[4], bh[NT], bl[NT];
#pragma unroll
            for (int m = 0; m < 4; ++m) {
                int row = wr * 64 + m * 16 + fr;
                int off = row * 64 + ((((kk << 2) + g) ^ (row & 7)) << 3);
                ah[m] = *(const f16x8*)(Ash + off);
                al4[m] = *(const f16x8*)(Asl + off);
            }
#pragma unroll
            for (int n = 0; n < NT; ++n) {
                int col = wc * (NT * 16) + n * 16 + fr;
                int off = col * 64 + ((((kk << 2) + g) ^ (col & 7)) << 3);
                bh[n] = *(const f16x8*)(Bsh + off);
                bl[n] = *(const f16x8*)(Bsl + off);
            }
#pragma unroll
            for (int m = 0; m < 4; ++m)
#pragma unroll
                for (int n = 0; n < NT; ++n) {
                    acc[m][n] = __builtin_amdgcn_mfma_f32_16x16x32_f16(ah[m], bh[n], acc[m][n], 0, 0, 0);
                    acc[m][n] = __builtin_amdgcn_mfma_f32_16x16x32_f16(ah[m], bl[n], acc[m][n], 0, 0, 0);
                    acc[m][n] = __builtin_amdgcn_mfma_f32_16x16x32_f16(al4[m], bh[n], acc[m][n], 0, 0, 0);
                }
        }
        __syncthreads();
    }
    if (part) {
        float* op = part + (size_t)blockIdx.z * mn;
#pragma unroll
        for (int m = 0; m < 4; ++m) {
            int row = m0 + wr * 64 + m * 16 + (g << 2);
#pragma unroll
            for (int n = 0; n < NT; ++n) {
                int col = n0 + wc * (NT * 16) + n * 16 + fr;
#pragma unroll
                for (int r = 0; r < 4; ++r)
                    op[(size_t)(row + r) * N + col] = acc[m][n][r];
            }
        }
    } else {
#pragma unroll
        for (int m = 0; m < 4; ++m) {
            int row = m0 + wr * 64 + m * 16 + (g << 2);
#pragma unroll
            for (int n = 0; n < NT; ++n) {
                int col = n0 + wc * (NT * 16) + n * 16 + fr;
                float bv = bias ? bias[col & bmask] : 0.f;
#pragma unroll
                for (int r = 0; r < 4; ++r) {
                    float v = acc[m][n][r] + bv;
                    v = apply_act(v, act);
                    size_t idx = (size_t)(row + r) * N + col;
                    if (Cl) {
                        _Float16 hh = (_Float16)v;
                        Ch[idx] = hh;
                        Cl[idx] = (_Float16)(v - (float)hh);
                    } else {
                        C[idx] = v;
                    }
                }
            }
        }
    }
}

// ---------------------------------------------------------------------------
// fp32 GEMM core (kept for RVQ / transformer)
// ---------------------------------------------------------------------------
template <int TM>
__device__ __forceinline__ void gemm_core(const float* __restrict__ A, int lda,
                                          const float* __restrict__ B, int N,
                                          int klen, int m0, int n0,
                                          float (&acc)[TM / 16][4]) {
    constexpr int RM = TM / 16;
    constexpr int AR = TM * 16 / 256;
    __shared__ float As[2][16][TM + 4];
    __shared__ float Bs[2][16][64];
    int tid = threadIdx.x;
    int tx = tid & 15, ty = tid >> 4;
    int bc = tid & 63, br0 = tid >> 6;
    int arow[AR], akk[AR];
#pragma unroll
    for (int i = 0; i < AR; i++) { int idx = tid + 256 * i; arow[i] = idx >> 4; akk[i] = idx & 15; }
    float areg[AR], breg[4];
#pragma unroll
    for (int i = 0; i < AR; i++) areg[i] = A[(size_t)(m0 + arow[i]) * lda + akk[i]];
#pragma unroll
    for (int i = 0; i < 4; i++) breg[i] = B[(size_t)(br0 + 4 * i) * N + n0 + bc];
#pragma unroll
    for (int i = 0; i < AR; i++) As[0][akk[i]][arow[i]] = areg[i];
#pragma unroll
    for (int i = 0; i < 4; i++) Bs[0][br0 + 4 * i][bc] = breg[i];
    __syncthreads();
    int nk = klen >> 4;
    for (int t = 0; t < nk; t++) {
        int cur = t & 1;
        if (t + 1 < nk) {
            int k0 = (t + 1) << 4;
#pragma unroll
            for (int i = 0; i < AR; i++) areg[i] = A[(size_t)(m0 + arow[i]) * lda + k0 + akk[i]];
#pragma unroll
            for (int i = 0; i < 4; i++) breg[i] = B[(size_t)(k0 + br0 + 4 * i) * N + n0 + bc];
        }
#pragma unroll
        for (int kk = 0; kk < 16; kk++) {
            float a[RM], b[4];
#pragma unroll
            for (int i = 0; i < RM; i++) a[i] = As[cur][kk][ty * RM + i];
#pragma unroll
            for (int j = 0; j < 4; j++) b[j] = Bs[cur][kk][tx * 4 + j];
#pragma unroll
            for (int i = 0; i < RM; i++)
#pragma unroll
                for (int j = 0; j < 4; j++) acc[i][j] += a[i] * b[j];
        }
        if (t + 1 < nk) {
            int nxt = cur ^ 1;
#pragma unroll
            for (int i = 0; i < AR; i++) As[nxt][akk[i]][arow[i]] = areg[i];
#pragma unroll
            for (int i = 0; i < 4; i++) Bs[nxt][br0 + 4 * i][bc] = breg[i];
            __syncthreads();
        }
    }
}

template <int TM>
__global__ __launch_bounds__(256) void k_gemm2(const float* __restrict__ A, int lda,
                                               const float* __restrict__ B,
                                               const float* __restrict__ bias, unsigned bmask,
                                               const float* __restrict__ res,
                                               const float* __restrict__ scale,
                                               float* __restrict__ C,
                                               float* __restrict__ part, long mn,
                                               int N, int klen, int act) {
    constexpr int RM = TM / 16;
    float acc[RM][4] = {};
    int m0 = blockIdx.x * TM, n0 = blockIdx.y * 64;
    int kz = blockIdx.z * klen;
    gemm_core<TM>(A + kz, lda, B + (size_t)kz * N, N, klen, m0, n0, acc);
    int tid = threadIdx.x;
    int tx = tid & 15, ty = tid >> 4;
    if (part) {
        float* out = part + (size_t)blockIdx.z * mn;
#pragma unroll
        for (int i = 0; i < RM; i++)
#pragma unroll
            for (int j = 0; j < 4; j++)
                out[(size_t)(m0 + ty * RM + i) * N + n0 + tx * 4 + j] = acc[i][j];
    } else {
#pragma unroll
        for (int i = 0; i < RM; i++) {
            int row = m0 + ty * RM + i;
#pragma unroll
            for (int j = 0; j < 4; j++) {
                int col = n0 + tx * 4 + j;
                float v = acc[i][j];
                if (bias) v += bias[col & bmask];
                v = apply_act(v, act);
                if (scale) v *= scale[col];
                if (res) v += res[(size_t)row * N + col];
                C[(size_t)row * N + col] = v;
            }
        }
    }
}

// Fused QKV with split-K=2: z = which*2 + s; raw partials.
__global__ __launch_bounds__(256) void k_qkv(const float* __restrict__ A,
                                             const float* __restrict__ B0,
                                             const float* __restrict__ B1,
                                             const float* __restrict__ B2,
                                             float* __restrict__ part) {
    int which = blockIdx.z >> 1, s = blockIdx.z & 1;
    const float* B = which == 0 ? B0 : (which == 1 ? B1 : B2);
    float acc[2][4] = {};
    int m0 = blockIdx.x * 32, n0 = blockIdx.y * 64;
    int kz = s * 256;
    gemm_core<32>(A + kz, 512, B + (size_t)kz * 512, 512, 256, m0, n0, acc);
    int tid = threadIdx.x;
    int tx = tid & 15, ty = tid >> 4;
    float* out = part + (size_t)blockIdx.z * (512 * 512);
#pragma unroll
    for (int i = 0; i < 2; i++)
#pragma unroll
        for (int j = 0; j < 4; j++)
            out[(size_t)(m0 + ty * 2 + i) * 512 + n0 + tx * 4 + j] = acc[i][j];
}

// ---------------------------------------------------------------------------
// Split-K reduce + epilogue (fp32 out)
// ---------------------------------------------------------------------------
__global__ __launch_bounds__(256) void k_reduce(const float* __restrict__ part, long mn, int S,
                                                const float* __restrict__ bias, unsigned bmask,
                                                const float* __restrict__ res,
                                                const float* __restrict__ scale,
                                                float* __restrict__ C, int N, int act) {
    long idx = ((long)blockIdx.x * 256 + threadIdx.x) * 4;
    if (idx >= mn) return;
    float4 v = *(const float4*)(part + idx);
    for (int s2 = 1; s2 < S; s2++) {
        float4 u = *(const float4*)(part + (size_t)s2 * mn + idx);
        v.x += u.x; v.y += u.y; v.z += u.z; v.w += u.w;
    }
    int col = (int)(idx % N);
    float vv[4] = {v.x, v.y, v.z, v.w};
#pragma unroll
    for (int j = 0; j < 4; j++) {
        float t = vv[j];
        int c = col + j;
        if (bias) t += bias[c & bmask];
        t = apply_act(t, act);
        if (scale) t *= scale[c];
        if (res) t += res[idx + j];
        vv[j] = t;
    }
    *(float4*)(C + idx) = make_float4(vv[0], vv[1], vv[2], vv[3]);
}

// Split-K reduce writing f16 hi/lo planes (bias -> act -> split)
__global__ __launch_bounds__(256) void k_reduce_h(const float* __restrict__ part, long mn, int S,
                                                  const float* __restrict__ bias, unsigned bmask,
                                                  _Float16* __restrict__ Ch,
                                                  _Float16* __restrict__ Cl, int N, int act) {
    long idx = ((long)blockIdx.x * 256 + threadIdx.x) * 4;
    if (idx >= mn) return;
    float4 v = *(const float4*)(part + idx);
    for (int s2 = 1; s2 < S; s2++) {
        float4 u = *(const float4*)(part + (size_t)s2 * mn + idx);
        v.x += u.x; v.y += u.y; v.z += u.z; v.w += u.w;
    }
    int col = (int)(idx % N);
    float vv[4] = {v.x, v.y, v.z, v.w};
    f16x4 h, l;
#pragma unroll
    for (int j = 0; j < 4; j++) {
        float t = vv[j];
        if (bias) t += bias[(col + j) & bmask];
        t = apply_act(t, act);
        _Float16 hh = (_Float16)t;
        h[j] = hh;
        l[j] = (_Float16)(t - (float)hh);
    }
    *(f16x4*)(Ch + idx) = h;
    *(f16x4*)(Cl + idx) = l;
}

__global__ __launch_bounds__(256) void k_reduce_qkv(const float* __restrict__ part,
                                                    float* __restrict__ q,
                                                    float* __restrict__ k,
                                                    float* __restrict__ v) {
    const long mn = 262144;
    int w = blockIdx.y;
    long idx = ((long)blockIdx.x * 256 + threadIdx.x) * 4;
    float4 a = *(const float4*)(part + (size_t)(2 * w) * mn + idx);
    float4 b = *(const float4*)(part + (size_t)(2 * w + 1) * mn + idx);
    float* C = w == 0 ? q : (w == 1 ? k : v);
    *(float4*)(C + idx) = make_float4(a.x + b.x, a.y + b.y, a.z + b.z, a.w + b.w);
}

// ---------------------------------------------------------------------------
// RMSNorm rows of x[M,N]
// ---------------------------------------------------------------------------
__global__ __launch_bounds__(256) void k_rms(const float* __restrict__ x,
                                             const float* __restrict__ g,
                                             float* __restrict__ y, int N) {
    int row = blockIdx.x;
    const float* xr = x + (size_t)row * N;
    int tid = threadIdx.x;
    float s = 0.f;
    for (int i = tid; i < N; i += 256) { float v = xr[i]; s += v * v; }
#pragma unroll
    for (int off = 32; off; off >>= 1) s += __shfl_xor(s, off);
    __shared__ float red[4];
    if ((tid & 63) == 0) red[tid >> 6] = s;
    __syncthreads();
    s = red[0] + red[1] + red[2] + red[3];
    float r = 1.0f / sqrtf(s / (float)N + 1e-6f);
    for (int i = tid; i < N; i += 256) y[(size_t)row * N + i] = xr[i] * r * g[i];
}

// ---------------------------------------------------------------------------
// Fused qk-norm + RoPE (cos/sin from precomputed table)
// ---------------------------------------------------------------------------
__global__ void k_qkrope2(float* __restrict__ q, float* __restrict__ k,
                          const float* __restrict__ gq, const float* __restrict__ gk,
                          const float* __restrict__ tab) {
    int bid = blockIdx.x;
    int t = bid >> 3, h = bid & 7;
    int d = threadIdx.x;
    float* p = (blockIdx.y == 0 ? q : k) + (size_t)t * D_DIM + h * HD;
    const float* g = blockIdx.y == 0 ? gq : gk;
    float val = p[d];
    float s = val * val;
#pragma unroll
    for (int off = 32; off; off >>= 1) s += __shfl_xor(s, off);
    float r = 1.0f / sqrtf(s * (1.0f / 64.0f) + 1e-6f);
    float y = val * r * g[d];
    int dm = d & 31;
    float c = tab[t * 32 + dm];
    float sn = tab[16384 + t * 32 + dm];
    float partner = __shfl_xor(y, 32);
    float out = (d < 32) ? (y * c - partner * sn) : (y * c + partner * sn);
    p[d] = out;
}

// ---------------------------------------------------------------------------
// MFMA flash attention (fp16x3 hi/lo = ~fp32 precision).
// ---------------------------------------------------------------------------
__global__ __launch_bounds__(128) void k_attn_mf(const float* __restrict__ q,
                                                 const float* __restrict__ k,
                                                 const float* __restrict__ v,
                                                 float* __restrict__ o) {
    __shared__ _Float16 Ph[2][16][32];
    __shared__ _Float16 Pl[2][16][32];
    __shared__ float mM[16], lM[16], OM[16][64];
    int h = blockIdx.x >> 5, qt = blockIdx.x & 31;
    int qr0 = qt << 4;
    int tid = threadIdx.x;
    int s = tid >> 6, lane = tid & 63;
    int fr = lane & 15, g = lane >> 4;
    int hoff = h * 64;

    f16x8 qh[2], ql[2];
    {
        const float* qp = q + (size_t)(qr0 + fr) * 512 + hoff + g * 8;
#pragma unroll
        for (int c = 0; c < 2; ++c) {
            float4 v0 = *(const float4*)(qp + c * 32);
            float4 v1 = *(const float4*)(qp + c * 32 + 4);
            float vv[8] = {v0.x, v0.y, v0.z, v0.w, v1.x, v1.y, v1.z, v1.w};
#pragma unroll
            for (int j = 0; j < 8; ++j) {
                float x = vv[j] * 0.125f;
                _Float16 hh = (_Float16)x;
                qh[c][j] = hh;
                ql[c][j] = (_Float16)(x - (float)hh);
            }
        }
    }

    float m_run = -3.4e38f, l_run = 0.f;
    f32x4 accO[4];
#pragma unroll
    for (int dt = 0; dt < 4; ++dt)
#pragma unroll
        for (int r = 0; r < 4; ++r) accO[dt][r] = 0.f;

    int nkt = (qr0 + 47) >> 5;
    for (int kt = s; kt < nkt; kt += 2) {
        int c0 = kt << 5;
        float sv[2][4];
        float mx = -3.4e38f;
#pragma unroll
        for (int t2 = 0; t2 < 2; ++t2) {
            const float* kp = k + (size_t)(c0 + t2 * 16 + fr) * 512 + hoff + g * 8;
            f16x8 kh[2], kl[2];
#pragma unroll
            for (int c = 0; c < 2; ++c) {
                float4 v0 = *(const float4*)(kp + c * 32);
                float4 v1 = *(const float4*)(kp + c * 32 + 4);
                float vv[8] = {v0.x, v0.y, v0.z, v0.w, v1.x, v1.y, v1.z, v1.w};
#pragma unroll
                for (int j = 0; j < 8; ++j) {
                    _Float16 hh = (_Float16)vv[j];
                    kh[c][j] = hh;
                    kl[c][j] = (_Float16)(vv[j] - (float)hh);
                }
            }
            f32x4 a;
#pragma unroll
            for (int r = 0; r < 4; ++r) a[r] = 0.f;
#pragma unroll
            for (int c = 0; c < 2; ++c) {
                a = __builtin_amdgcn_mfma_f32_16x16x32_f16(kh[c], qh[c], a, 0, 0, 0);
                a = __builtin_amdgcn_mfma_f32_16x16x32_f16(kh[c], ql[c], a, 0, 0, 0);
                a = __builtin_amdgcn_mfma_f32_16x16x32_f16(kl[c], qh[c], a, 0, 0, 0);
            }
#pragma unroll
            for (int r = 0; r < 4; ++r) {
                int key = c0 + t2 * 16 + g * 4 + r;
                float x = (key <= qr0 + fr) ? a[r] : -3.4e38f;
                sv[t2][r] = x;
                mx = fmaxf(mx, x);
            }
        }
        mx = fmaxf(mx, __shfl_xor(mx, 16));
        mx = fmaxf(mx, __shfl_xor(mx, 32));
        float m_new = fmaxf(m_run, mx);
        float alpha = __expf(m_run - m_new);
        l_run *= alpha;
        float ar[4];
#pragma unroll
        for (int r = 0; r < 4; ++r) ar[r] = __shfl(alpha, g * 4 + r);
#pragma unroll
        for (int dt = 0; dt < 4; ++dt)
#pragma unroll
            for (int r = 0; r < 4; ++r) accO[dt][r] *= ar[r];
        float psum = 0.f;
#pragma unroll
        for (int t2 = 0; t2 < 2; ++t2) {
            f16x4 ph4, pl4;
#pragma unroll
            for (int r = 0; r < 4; ++r) {
                float p = __expf(sv[t2][r] - m_new);
                psum += p;
                _Float16 hh = (_Float16)p;
                ph4[r] = hh;
                pl4[r] = (_Float16)(p - (float)hh);
            }
            *(f16x4*)(&Ph[s][fr][t2 * 16 + g * 4]) = ph4;
            *(f16x4*)(&Pl[s][fr][t2 * 16 + g * 4]) = pl4;
        }
        psum += __shfl_xor(psum, 16);
        psum += __shfl_xor(psum, 32);
        l_run += psum;
        m_run = m_new;
        f16x8 pah = *(const f16x8*)(&Ph[s][fr][g * 8]);
        f16x8 pal = *(const f16x8*)(&Pl[s][fr][g * 8]);
#pragma unroll
        for (int dt = 0; dt < 4; ++dt) {
            const float* vp = v + (size_t)(c0 + g * 8) * 512 + hoff + dt * 16 + fr;
            f16x8 bh, bl;
#pragma unroll
            for (int j = 0; j < 8; ++j) {
                float x = vp[(size_t)j * 512];
                _Float16 hh = (_Float16)x;
                bh[j] = hh;
                bl[j] = (_Float16)(x - (float)hh);
            }
            accO[dt] = __builtin_amdgcn_mfma_f32_16x16x32_f16(pah, bh, accO[dt], 0, 0, 0);
            accO[dt] = __builtin_amdgcn_mfma_f32_16x16x32_f16(pah, bl, accO[dt], 0, 0, 0);
            accO[dt] = __builtin_amdgcn_mfma_f32_16x16x32_f16(pal, bh, accO[dt], 0, 0, 0);
        }
    }
    if (s == 1) {
        if (g == 0) { mM[fr] = m_run; lM[fr] = l_run; }
#pragma unroll
        for (int dt = 0; dt < 4; ++dt)
#pragma unroll
            for (int r = 0; r < 4; ++r)
                OM[g * 4 + r][dt * 16 + fr] = accO[dt][r];
    }
    __syncthreads();
    if (s == 0) {
        float m1 = mM[fr], l1 = lM[fr];
        float mf = fmaxf(m_run, m1);
        float a0 = __expf(m_run - mf), a1 = __expf(m1 - mf);
        float lf = l_run * a0 + l1 * a1;
        float inv = 1.0f / lf;
        float a0r[4], a1r[4], invr[4];
#pragma unroll
        for (int r = 0; r < 4; ++r) {
            a0r[r] = __shfl(a0, g * 4 + r);
            a1r[r] = __shfl(a1, g * 4 + r);
            invr[r] = __shfl(inv, g * 4 + r);
        }
#pragma unroll
        for (int dt = 0; dt < 4; ++dt)
#pragma unroll
            for (int r = 0; r < 4; ++r) {
                float ov = (accO[dt][r] * a0r[r] + OM[g * 4 + r][dt * 16 + fr] * a1r[r]) * invr[r];
                o[(size_t)(qr0 + g * 4 + r) * 512 + hoff + dt * 16 + fr] = ov;
            }
    }
}

// ---------------------------------------------------------------------------
// Final conv: Cin=32 -> 1, K=7 SAME, clip
// ---------------------------------------------------------------------------
__global__ __launch_bounds__(256) void k_conv_fin(const float* __restrict__ x,
                                                  const float* __restrict__ w,
                                                  const float* __restrict__ b,
                                                  float* __restrict__ y, int n) {
    __shared__ float xs[262 * 33];
    __shared__ float wsm[224];
    int tid = threadIdx.x;
    int o0 = blockIdx.x * 256;
    for (int i = tid; i < 262 * 32; i += 256) {
        int r = i >> 5, c = i & 31;
        int t = o0 - 3 + r;
        xs[r * 33 + c] = (t >= 0 && t < n) ? x[(size_t)t * 32 + c] : 0.f;
    }
    if (tid < 224) wsm[tid] = w[tid];
    __syncthreads();
    float acc = b[0];
#pragma unroll
    for (int kk = 0; kk < 7; kk++)
#pragma unroll
        for (int ci = 0; ci < 32; ci++)
            acc += xs[(tid + kk) * 33 + ci] * wsm[kk * 32 + ci];
    y[o0 + tid] = fminf(fmaxf(acc, -1.f), 1.f);
}

// ---------------------------------------------------------------------------
// Host helpers
// ---------------------------------------------------------------------------
static inline void gemmS64(hipStream_t st, const float* A, int lda, const float* B,
                           const float* bias, unsigned bmask, const float* res,
                           const float* scale, float* C, float* part,
                           int M, int N, int K, int S, int act) {
    long mn = (long)M * N;
    if (S > 1) {
        k_gemm2<64><<<dim3(M / 64, N / 64, S), 256, 0, st>>>(
            A, lda, B, nullptr, 0, nullptr, nullptr, nullptr, part, mn, N, K / S, 0);
        k_reduce<<<dim3((int)(mn / 1024)), 256, 0, st>>>(
            part, mn, S, bias, bmask, res, scale, C, N, act);
    } else {
        k_gemm2<64><<<dim3(M / 64, N / 64, 1), 256, 0, st>>>(
            A, lda, B, bias, bmask, res, scale, C, nullptr, mn, N, K, act);
    }
}
static inline void gemmS32(hipStream_t st, const float* A, int lda, const float* B,
                           const float* bias, unsigned bmask, const float* res,
                           const float* scale, float* C, float* part,
                           int M, int N, int K, int S, int act) {
    long mn = (long)M * N;
    if (S > 1) {
        k_gemm2<32><<<dim3(M / 32, N / 64, S), 256, 0, st>>>(
            A, lda, B, nullptr, 0, nullptr, nullptr, nullptr, part, mn, N, K / S, 0);
        k_reduce<<<dim3((int)(mn / 1024)), 256, 0, st>>>(
            part, mn, S, bias, bmask, res, scale, C, N, act);
    } else {
        k_gemm2<32><<<dim3(M / 32, N / 64, 1), 256, 0, st>>>(
            A, lda, B, bias, bmask, res, scale, C, nullptr, mn, N, K, act);
    }
}

extern "C" void kernel_launch(void* const* d_in, const int* in_sizes, int n_in,
                              void* d_out, int out_size, void* d_ws, size_t ws_size,
                              hipStream_t stream) {
    int i = 0;
    const int*   codes     = (const int*)  d_in[i++];
    const float* emb_first = (const float*)d_in[i++];
    const float* pf_w      = (const float*)d_in[i++];
    const float* pf_b      = (const float*)d_in[i++];
    const float* fo_w      = (const float*)d_in[i++];
    const float* fo_b      = (const float*)d_in[i++];
    const float* emb_rest  = (const float*)d_in[i++];
    const float* pr_w      = (const float*)d_in[i++];
    const float* pr_b      = (const float*)d_in[i++];
    const float* ro_w      = (const float*)d_in[i++];
    const float* ro_b      = (const float*)d_in[i++];
    const float* pre_w     = (const float*)d_in[i++];
    const float* pre_b     = (const float*)d_in[i++];
    const float* in_w      = (const float*)d_in[i++];
    const float* in_b      = (const float*)d_in[i++];
    const float* ln1       = (const float*)d_in[i++];
    const float* qw        = (const float*)d_in[i++];
    const float* kw        = (const float*)d_in[i++];
    const float* vw        = (const float*)d_in[i++];
    const float* ow        = (const float*)d_in[i++];
    const float* qn        = (const float*)d_in[i++];
    const float* kn        = (const float*)d_in[i++];
    const float* ls_a      = (const float*)d_in[i++];
    const float* ln2       = (const float*)d_in[i++];
    const float* w1        = (const float*)d_in[i++];
    const float* w2        = (const float*)d_in[i++];
    const float* ls_m      = (const float*)d_in[i++];
    const float* fn_w      = (const float*)d_in[i++];
    const float* out_w     = (const float*)d_in[i++];
    const float* out_b     = (const float*)d_in[i++];
    const float* up_w      = (const float*)d_in[i++];
    const float* up_b      = (const float*)d_in[i++];
    const float* dec0_w    = (const float*)d_in[i++];
    const float* dec0_b    = (const float*)d_in[i++];
    const float* dw1       = (const float*)d_in[i++];
    const float* db1       = (const float*)d_in[i++];
    const float* dw2       = (const float*)d_in[i++];
    const float* db2       = (const float*)d_in[i++];
    const float* dw3       = (const float*)d_in[i++];
    const float* db3       = (const float*)d_in[i++];
    const float* dw4       = (const float*)d_in[i++];
    const float* db4       = (const float*)d_in[i++];
    const float* fin_w     = (const float*)d_in[i++];
    const float* fin_b     = (const float*)d_in[i++];

    float* ws = (float*)d_ws;
    float* outp = (float*)d_out;

    float* qf_pre   = ws + WS_QFPRE;
    float* G        = ws + WS_G;
    float* qf       = ws + WS_QF;
    float* tA       = ws + WS_TA;
    float* hidden   = ws + WS_HID;
    float* conv_out = ws + WS_CONV;
    float* h        = ws + WS_H;
    float* x        = ws + WS_X;
    float* qb       = ws + WS_QB;
    float* kb       = ws + WS_KB;
    float* vb       = ws + WS_VB;
    float* attnb    = ws + WS_ATT;
    float* ff       = ws + WS_FF;
    float* bias_sum = ws + WS_BSUM;
    float* houtp    = ws + WS_HOUT;
    float* t4       = ws + WS_T4;
    float* part     = ws + WS_PART;
    float* ropetab  = ws + WS_ROPE;

    // f16 plane data pointers
    _Float16* up16h = (_Float16*)(ws + UP16H_D);
    _Float16* up16l = (_Float16*)(ws + UP16L_D);
    _Float16* dec16h = (_Float16*)(ws + DEC16H_D);
    _Float16* dec16l = (_Float16*)(ws + DEC16L_D);
    _Float16* t1h = (_Float16*)(ws + T1H_D);
    _Float16* t1l = (_Float16*)(ws + T1L_D);
    _Float16* t2h = (_Float16*)(ws + T2H_D);
    _Float16* t2l = (_Float16*)(ws + T2L_D);
    _Float16* t3h = (_Float16*)(ws + T3H_D);
    _Float16* t3l = (_Float16*)(ws + T3L_D);

    // f16 hi/lo transposed weight planes
    _Float16* BTup_h = (_Float16*)(ws + WS_W2UP);   _Float16* BTup_l = BTup_h + 2048 * 3072;
    _Float16* BTd1_h = (_Float16*)(ws + WS_W2D1);   _Float16* BTd1_l = BTd1_h + 2048 * 1536;
    _Float16* BTd2_h = (_Float16*)(ws + WS_W2D2);   _Float16* BTd2_l = BTd2_h + 768 * 768;
    _Float16* BTd3_h = (_Float16*)(ws + WS_W2D3);   _Float16* BTd3_l = BTd3_h + 320 * 384;
    _Float16* BTd4_h = (_Float16*)(ws + WS_W2D4);   _Float16* BTd4_l = BTd4_h + 128 * 192;
    _Float16* BTd0_h = (_Float16*)(ws + WS_DEC0B16);_Float16* BTd0_l = BTd0_h + 512 * 7168;
    _Float16* BTpr_h = (_Float16*)(ws + WS_BTPR);   _Float16* BTpr_l = BTpr_h + 1024 * 3840;

    // --- prep ---
    k_zero_guards<<<15, 256, 0, stream>>>(ws);
    k_rope_tab<<<64, 256, 0, stream>>>(ropetab);
    k_wt16<<<dim3(32, 24), 256, 0, stream>>>(up_w, BTup_h, BTup_l, 1024, 1024, 2, 2);
    k_wt16<<<dim3(32, 12), 256, 0, stream>>>(dw1, BTd1_h, BTd1_l, 512, 256, 8, 11);
    k_wt16<<<dim3(12, 6), 256, 0, stream>>>(dw2, BTd2_h, BTd2_l, 256, 128, 6, 8);
    k_wt16<<<dim3(5, 3), 256, 0, stream>>>(dw3, BTd3_h, BTd3_l, 128, 64, 5, 7);
    k_wt16<<<dim3(2, 2), 256, 0, stream>>>(dw4, BTd4_h, BTd4_l, 64, 32, 4, 5);
    k_bt16<<<dim3(8, 56), 256, 0, stream>>>(dec0_w, BTd0_h, BTd0_l, 7168, 512);
    k_bt16<<<dim3(16, 30), 256, 0, stream>>>(pr_w, BTpr_h, BTpr_l, 3840, 1024);

    // --- RVQ decode ---
    k_gather<<<8192, 256, 0, stream>>>(codes, emb_first, emb_rest, qf_pre, G);
    k_bias_sum<<<4, 256, 0, stream>>>(pr_b, bias_sum);
    gemmS64(stream, qf_pre, 256, pf_w, pf_b, ~0u, nullptr, nullptr, tA, part, 512, 1024, 256, 2, 0);
    gemmS64(stream, tA, 1024, fo_w, fo_b, ~0u, nullptr, nullptr, qf, part, 512, 1024, 1024, 4, 0);
    k_gemm16<<<dim3(4, 16, 4), 256, 0, stream>>>(G, 3840, BTpr_h, BTpr_l, 3840,
            nullptr, 0, nullptr, part, 524288L, 1024, 960, 0);
    k_reduce<<<512, 256, 0, stream>>>(part, 524288L, 4, bias_sum, ~0u, nullptr, nullptr,
            tA, 1024, 0);
    gemmS64(stream, tA, 1024, ro_w, ro_b, ~0u, qf, nullptr, hidden, part, 512, 1024, 1024, 4, 0);

    // --- causal pre-conv (k=3) via windowed GEMM ---
    gemmS64(stream, hidden - 2048, 1024, pre_w, pre_b, ~0u, nullptr, nullptr,
            conv_out, part, 512, 1024, 3072, 8, 0);

    // --- transformer input proj ---
    gemmS32(stream, conv_out, 1024, in_w, in_b, ~0u, nullptr, nullptr, h, part, 512, 512, 1024, 4, 0);

    // --- 8 transformer layers ---
    for (int l = 0; l < NL; l++) {
        const float* qw_l = qw + (size_t)l * D_DIM * D_DIM;
        const float* kw_l = kw + (size_t)l * D_DIM * D_DIM;
        const float* vw_l = vw + (size_t)l * D_DIM * D_DIM;
        const float* ow_l = ow + (size_t)l * D_DIM * D_DIM;
        const float* w1_l = w1 + (size_t)l * D_DIM * FF_D;
        const float* w2_l = w2 + (size_t)l * FF_D * D_DIM;

        k_rms<<<512, 256, 0, stream>>>(h, ln1 + l * D_DIM, x, D_DIM);
        k_qkv<<<dim3(16, 8, 6), 256, 0, stream>>>(x, qw_l, kw_l, vw_l, part);
        k_reduce_qkv<<<dim3(256, 3), 256, 0, stream>>>(part, qb, kb, vb);
        k_qkrope2<<<dim3(T_LEN * NH, 2), 64, 0, stream>>>(qb, kb, qn + l * HD, kn + l * HD, ropetab);
        k_attn_mf<<<256, 128, 0, stream>>>(qb, kb, vb, attnb);
        gemmS32(stream, attnb, 512, ow_l, nullptr, 0, h, ls_a + l * D_DIM, h, part,
                512, 512, 512, 2, 0);
        k_rms<<<512, 256, 0, stream>>>(h, ln2 + l * D_DIM, x, D_DIM);
        gemmS64(stream, x, 512, w1_l, nullptr, 0, nullptr, nullptr, ff, part,
                512, 2048, 512, 2, 1);
        gemmS32(stream, ff, 2048, w2_l, nullptr, 0, h, ls_m + l * D_DIM, h, part,
                512, 512, 2048, 8, 0);
    }

    // --- final norm + out proj ---
    k_rms<<<512, 256, 0, stream>>>(h, fn_w, x, D_DIM);
    gemmS64(stream, x, 512, out_w, out_b, ~0u, nullptr, nullptr, houtp, part, 512, 1024, 512, 4, 0);

    // --- upsample x2 convT (fp32 A), elu; split-K=2 -> f16 planes ---
    k_gemm16<<<dim3(4, 32, 2), 256, 0, stream>>>(houtp - 1024, 1024, BTup_h, BTup_l, 3072,
            nullptr, 0, nullptr, part, 1048576L, 2048, 1536, 0);
    k_reduce_h<<<1024, 256, 0, stream>>>(part, 1048576L, 2, up_b, 1023u,
            up16h, up16l, 2048, 2);

    // --- dec0 conv k=7 SAME (plane A), elu; split-K=8 -> f16 planes ---
    k_gemm16h<4><<<dim3(8, 4, 8), 256, 0, stream>>>(up16h - 3072, up16l - 3072, 1024,
            BTd0_h, BTd0_l, 7168, nullptr, 0, nullptr, nullptr, nullptr,
            part, 524288L, 512, 896, 0);
    k_reduce_h<<<512, 256, 0, stream>>>(part, 524288L, 8, dec0_b, ~0u,
            dec16h, dec16l, 512, 2);
    k_zero2<<<8, 256, 0, stream>>>(ws);

    // --- SEANet convT chain (plane A -> plane out), elu ---
    k_gemm16h<2><<<dim3(8, 32, 1), 256, 0, stream>>>(dec16h - 512, dec16l - 512, 512,
            BTd1_h, BTd1_l, 1536, db1, 255u, nullptr, t1h, t1l, nullptr, 0L, 2048, 1536, 2);
    k_gemm16h<4><<<dim3(64, 6, 1), 256, 0, stream>>>(t1h - 256, t1l - 256, 256,
            BTd2_h, BTd2_l, 768, db2, 127u, nullptr, t2h, t2l, nullptr, 0L, 768, 768, 2);
    k_gemm16h<2><<<dim3(384, 5, 1), 256, 0, stream>>>(t2h - 128, t2l - 128, 128,
            BTd3_h, BTd3_l, 384, db3, 63u, nullptr, t3h, t3l, nullptr, 0L, 320, 384, 2);
    k_gemm16h<4><<<dim3(1920, 1, 1), 256, 0, stream>>>(t3h - 64, t3l - 64, 64,
            BTd4_h, BTd4_l, 192, db4, 31u, t4, nullptr, nullptr, nullptr, 0L, 128, 192, 2);

    // --- final conv ---
    k_conv_fin<<<983040 / 256, 256, 0, stream>>>(t4, fin_w, fin_b, outp, 983040);
}

// Round 5
// 1898.089 us; speedup vs baseline: 1.7068x; 1.0570x over previous
//
#include <hip/hip_runtime.h>
#include <hip/hip_bf16.h>
#include <math.h>

#define T_LEN 512
#define LAT   1024
#define D_DIM 512
#define NH    8
#define HD    64
#define FF_D  2048
#define NL    8
#define NQ    16

typedef _Float16 f16x4 __attribute__((ext_vector_type(4)));
typedef _Float16 f16x8 __attribute__((ext_vector_type(8)));
typedef float    f32x4 __attribute__((ext_vector_type(4)));

// ---------------------------------------------------------------------------
// Workspace layout (float offsets)
// ---------------------------------------------------------------------------
#define WS_QFPRE    0
#define WS_G        131072
#define WS_QF       2097152
#define WS_TA       2621440
#define WS_HIDG     3145728            // 2048 guard floats before hidden
#define WS_HID      3147776
#define WS_CONV     3672064
#define WS_H        4196352
#define WS_X        4458496
#define WS_QB       4720640
#define WS_KB       4982784
#define WS_VB       5244928
#define WS_ATT      5507072
#define WS_FF       5769216
#define WS_BSUM     6817792
#define WS_HOUT     6819840            // guard 1024 at 6818816, post at 7344128
// f16 hi/lo plane buffers for the tail chain (same footprint as old fp32).
#define UP16H_D   7346688
#define UP16L_D   7874048
#define DEC16H_D  8400128
#define DEC16L_D  8662784
#define T1H_D     8925312
#define T1L_D     9974144
#define T2H_D     11022912
#define T2L_D     14168768
#define T3H_D     31457312
#define T3L_D     39321696
#define WS_W2UP     17314560           // 6291456 floats -> f16 hi/lo planes
#define WS_W2D1     23606016           // 3145728
#define WS_W2D2     26751744           // 589824
#define WS_W2D3     27341568           // 122880
#define WS_W2D4     47186048           // 24576 -> ends 47210624
#define WS_T4       0                  // aliases phase-A region (dead by then)
// dec0 transposed f16 weights: aliases t2 data region.
#define WS_DEC0B16  11022976
// split-K partials: alias t3 data region (dead until d3 writes it)
#define WS_PART     31457344
// pr_w transposed f16 planes (consumed in RVQ, clobbered later by t3 planes)
#define WS_BTPR     35651712
// RoPE cos/sin table
#define WS_ROPE     39583872
// Layer-weight / pre / in / out f16 planes: ws+0 .. 3,145,728 floats.
// Live only between RVQ end and tail start (t4 clobbers at the very end).

// ---------------------------------------------------------------------------
// Guard zeroing (ws is poisoned before every launch).
// ---------------------------------------------------------------------------
__global__ void k_zero_guards(float* __restrict__ ws) {
    const int offs[15] = {3145728, 6818816, 7344128,
                          7345152, 7870976, 7872512, 8398336,
                          8399872, 8662272, 8662528, 8924928,
                          8925184, 9973888, 9974016, 11022720};
    const int lens[15] = {2048, 1024, 1024,
                          1536, 1536, 1536, 1536,
                          256, 256, 256, 256,
                          128, 128, 128, 128};
    int r = blockIdx.x;
    for (int i = threadIdx.x; i < lens[r]; i += 256) ws[offs[r] + i] = 0.f;
}

// t2/t3 plane guards: zeroed after BTd0 / BTpr / max-part usage are dead.
__global__ void k_zero2(float* __restrict__ ws) {
    const int offs[8] = {11022848, 14168640, 14168704, 17314496,
                         31457280, 39321632, 39321664, 47186016};
    const int lens[8] = {64, 64, 64, 64, 32, 32, 32, 32};
    int r = blockIdx.x;
    for (int i = threadIdx.x; i < lens[r]; i += 256) ws[offs[r] + i] = 0.f;
}

// ---------------------------------------------------------------------------
// Gathers
// ---------------------------------------------------------------------------
__global__ __launch_bounds__(256) void k_gather(const int* __restrict__ codes,
                                                const float* __restrict__ emb_first,
                                                const float* __restrict__ emb_rest,
                                                float* __restrict__ qf_pre,
                                                float* __restrict__ G) {
    int idx = blockIdx.x * 256 + threadIdx.x;
    int c = idx & 255;
    int r = (idx >> 8) & 15;
    int t = idx >> 12;
    if (t >= T_LEN) return;
    if (r == 0) {
        int code = codes[t];
        qf_pre[t * 256 + c] = emb_first[code * 256 + c];
    } else {
        int n = r - 1;
        int code = codes[(n + 1) * T_LEN + t];
        G[t * 3840 + n * 256 + c] = emb_rest[(n * 2048 + code) * 256 + c];
    }
}

__global__ void k_bias_sum(const float* __restrict__ pr_b, float* __restrict__ out) {
    int d = blockIdx.x * 256 + threadIdx.x;
    if (d >= LAT) return;
    float s = 0.f;
    for (int n = 0; n < NQ - 1; n++) s += pr_b[n * LAT + d];
    out[d] = s;
}

// RoPE cos/sin table
__global__ void k_rope_tab(float* __restrict__ tab) {
    int idx = blockIdx.x * 256 + threadIdx.x;
    int t = idx >> 5, dm = idx & 31;
    double inv = pow(10000.0, -(double)dm / 32.0);
    double ang = (double)t * inv;
    tab[idx] = (float)cos(ang);
    tab[16384 + idx] = (float)sin(ang);
}

// ---------------------------------------------------------------------------
// convT weight transform -> TRANSPOSED f16 hi/lo planes [N=s*Cout][K3=3*Cin].
// ---------------------------------------------------------------------------
__global__ __launch_bounds__(256) void k_wt16(const float* __restrict__ w,
                                              _Float16* __restrict__ bth,
                                              _Float16* __restrict__ btl,
                                              int Cin, int Cout, int s, int pad_a) {
    int K3 = 3 * Cin;
    int col = blockIdx.x * 64 + (threadIdx.x & 63);
    int rk0 = blockIdx.y * 128 + (threadIdx.x >> 6) * 32;
    if (rk0 >= K3) return;
    int p = col / Cout, co = col - p * Cout;
    int kk0 = (pad_a - p) % s;
    if (kk0 < 0) kk0 += s;
    int cp = (p + kk0 - pad_a) / s;
    size_t ob = (size_t)col * K3 + rk0;
    for (int rb = 0; rb < 32; rb += 4) {
        f16x4 h, l;
#pragma unroll
        for (int j2 = 0; j2 < 4; ++j2) {
            int rowk = rk0 + rb + j2;
            int j = rowk / Cin, ci = rowk - j * Cin;
            int d = j - 1;
            float v = 0.f;
            if (d == cp) v = w[((size_t)kk0 * Cin + ci) * Cout + co];
            else if (d == cp + 1) v = w[((size_t)(kk0 + s) * Cin + ci) * Cout + co];
            _Float16 hh = (_Float16)v;
            h[j2] = hh;
            l[j2] = (_Float16)(v - (float)hh);
        }
        *(f16x4*)(bth + ob + rb) = h;
        *(f16x4*)(btl + ob + rb) = l;
    }
}

// Plain transpose+split: [K][N] fp32 -> [N][K] f16 hi/lo
__global__ __launch_bounds__(256) void k_bt16(const float* __restrict__ w,
                                              _Float16* __restrict__ bth,
                                              _Float16* __restrict__ btl,
                                              int K, int N) {
    int col = blockIdx.x * 64 + (threadIdx.x & 63);
    int rk0 = blockIdx.y * 128 + (threadIdx.x >> 6) * 32;
    size_t ob = (size_t)col * K + rk0;
    for (int rb = 0; rb < 32; rb += 4) {
        f16x4 h, l;
#pragma unroll
        for (int j2 = 0; j2 < 4; ++j2) {
            float v = w[(size_t)(rk0 + rb + j2) * N + col];
            _Float16 hh = (_Float16)v;
            h[j2] = hh;
            l[j2] = (_Float16)(v - (float)hh);
        }
        *(f16x4*)(bth + ob + rb) = h;
        *(f16x4*)(btl + ob + rb) = l;
    }
}

// ---------------------------------------------------------------------------
// Fused per-layer weight transform: qw,kw,vw,ow [512][512], w1 [512][2048],
// w2 [2048][512] -> transposed f16 hi/lo planes in LW.
// LW f16 layout: q_h 0, q_l 262144, k_h 524288, k_l 786432, v_h 1048576,
// v_l 1310720, o_h 1572864, o_l 1835008, w1_h 2097152, w1_l 3145728,
// w2_h 4194304, w2_l 5242880 (end 6291456 f16 = 3,145,728 floats).
// ---------------------------------------------------------------------------
__global__ __launch_bounds__(256) void k_ltw(const float* __restrict__ qw,
                                             const float* __restrict__ kw,
                                             const float* __restrict__ vw,
                                             const float* __restrict__ ow,
                                             const float* __restrict__ w1,
                                             const float* __restrict__ w2,
                                             _Float16* __restrict__ LW) {
    int b = blockIdx.x;
    const float* src; _Float16 *dh, *dl; int K, N, colb, rkb;
    if (b < 128) {
        int which = b >> 5, sub = b & 31;
        src = which == 0 ? qw : which == 1 ? kw : which == 2 ? vw : ow;
        K = 512; N = 512; colb = sub & 7; rkb = sub >> 3;
        dh = LW + which * 524288; dl = dh + 262144;
    } else if (b < 256) {
        int sub = b - 128;
        src = w1; K = 512; N = 2048; colb = sub & 31; rkb = sub >> 5;
        dh = LW + 2097152; dl = LW + 3145728;
    } else {
        int sub = b - 256;
        src = w2; K = 2048; N = 512; colb = sub & 7; rkb = sub >> 3;
        dh = LW + 4194304; dl = LW + 5242880;
    }
    int tid = threadIdx.x;
    int col = colb * 64 + (tid & 63);
    int rk0 = rkb * 128 + (tid >> 6) * 32;
    size_t ob = (size_t)col * K + rk0;
    for (int rb = 0; rb < 32; rb += 8) {
        f16x8 h, l;
#pragma unroll
        for (int j = 0; j < 8; ++j) {
            float v = src[(size_t)(rk0 + rb + j) * N + col];
            _Float16 hh = (_Float16)v;
            h[j] = hh;
            l[j] = (_Float16)(v - (float)hh);
        }
        *(f16x8*)(dh + ob + rb) = h;
        *(f16x8*)(dl + ob + rb) = l;
    }
}

__device__ __forceinline__ float apply_act(float v, int act) {
    if (act == 1) return 0.5f * v * (1.0f + erff(v * 0.70710678118654752440f));
    if (act == 2) return v > 0.f ? v : expm1f(v);
    return v;
}

// ---------------------------------------------------------------------------
// fp16x3 MFMA GEMM core: fp32 A split on the fly into swizzled LDS; B from
// pre-transposed f16 hi/lo planes [N][Kfull]. Tile 128x64, BK=64, 4 waves.
// ---------------------------------------------------------------------------
__device__ __forceinline__ void mf_core(const float* __restrict__ Ab, int lda,
                                        const _Float16* __restrict__ BTh,
                                        const _Float16* __restrict__ BTl, int ldb,
                                        int m0, int n0, int kz, int klen,
                                        f32x4 (&acc)[4][2],
                                        _Float16* Ash, _Float16* Asl,
                                        _Float16* Bsh, _Float16* Bsl) {
    int tid = threadIdx.x;
    int lane = tid & 63, wv = tid >> 6;
    int wr = wv >> 1, wc = wv & 1;
    int fr = lane & 15, g = lane >> 4;
    int nk = klen >> 6;
    for (int t = 0; t < nk; ++t) {
        int k0 = t << 6;
#pragma unroll
        for (int i2 = 0; i2 < 8; ++i2) {
            int c = tid + 256 * i2;
            int row = c >> 4, kc = c & 15;
            float4 v = *(const float4*)(Ab + (size_t)(m0 + row) * lda + k0 + (kc << 2));
            f16x4 h, l;
            float vv[4] = {v.x, v.y, v.z, v.w};
#pragma unroll
            for (int j = 0; j < 4; ++j) {
                _Float16 hh = (_Float16)vv[j];
                h[j] = hh;
                l[j] = (_Float16)(vv[j] - (float)hh);
            }
            int off = row * 64 + (((kc >> 1) ^ (row & 7)) << 3) + ((kc & 1) << 2);
            *(f16x4*)(Ash + off) = h;
            *(f16x4*)(Asl + off) = l;
        }
#pragma unroll
        for (int i2 = 0; i2 < 2; ++i2) {
            int c = tid + 256 * i2;
            int col = c >> 3, s = c & 7;
            size_t goff = (size_t)(n0 + col) * ldb + kz + k0 + (s << 3);
            f16x8 hv = *(const f16x8*)(BTh + goff);
            f16x8 lv = *(const f16x8*)(BTl + goff);
            int off = col * 64 + ((s ^ (col & 7)) << 3);
            *(f16x8*)(Bsh + off) = hv;
            *(f16x8*)(Bsl + off) = lv;
        }
        __syncthreads();
#pragma unroll
        for (int kk = 0; kk < 2; ++kk) {
            f16x8 ah[4], al[4], bh[2], bl[2];
#pragma unroll
            for (int m = 0; m < 4; ++m) {
                int row = wr * 64 + m * 16 + fr;
                int off = row * 64 + ((((kk << 2) + g) ^ (row & 7)) << 3);
                ah[m] = *(const f16x8*)(Ash + off);
                al[m] = *(const f16x8*)(Asl + off);
            }
#pragma unroll
            for (int n = 0; n < 2; ++n) {
                int col = wc * 32 + n * 16 + fr;
                int off = col * 64 + ((((kk << 2) + g) ^ (col & 7)) << 3);
                bh[n] = *(const f16x8*)(Bsh + off);
                bl[n] = *(const f16x8*)(Bsl + off);
            }
#pragma unroll
            for (int m = 0; m < 4; ++m)
#pragma unroll
                for (int n = 0; n < 2; ++n) {
                    acc[m][n] = __builtin_amdgcn_mfma_f32_16x16x32_f16(ah[m], bh[n], acc[m][n], 0, 0, 0);
                    acc[m][n] = __builtin_amdgcn_mfma_f32_16x16x32_f16(ah[m], bl[n], acc[m][n], 0, 0, 0);
                    acc[m][n] = __builtin_amdgcn_mfma_f32_16x16x32_f16(al[m], bh[n], acc[m][n], 0, 0, 0);
                }
        }
        __syncthreads();
    }
}

__global__ __launch_bounds__(256) void k_gemm16(const float* __restrict__ A, int lda,
                                                const _Float16* __restrict__ BTh,
                                                const _Float16* __restrict__ BTl, int ldb,
                                                const float* __restrict__ bias, unsigned bmask,
                                                float* __restrict__ C,
                                                float* __restrict__ part, long mn,
                                                int N, int klen, int act) {
    __shared__ _Float16 Ash[128 * 64];
    __shared__ _Float16 Asl[128 * 64];
    __shared__ _Float16 Bsh[64 * 64];
    __shared__ _Float16 Bsl[64 * 64];
    int m0 = blockIdx.x * 128, n0 = blockIdx.y * 64;
    int kz = blockIdx.z * klen;
    f32x4 acc[4][2];
#pragma unroll
    for (int m = 0; m < 4; ++m)
#pragma unroll
        for (int n = 0; n < 2; ++n)
#pragma unroll
            for (int r = 0; r < 4; ++r) acc[m][n][r] = 0.f;
    mf_core(A + kz, lda, BTh, BTl, ldb, m0, n0, kz, klen, acc, Ash, Asl, Bsh, Bsl);
    int tid = threadIdx.x;
    int lane = tid & 63, wv = tid >> 6;
    int wr = wv >> 1, wc = wv & 1;
    int fr = lane & 15, g = lane >> 4;
    if (part) {
        float* op = part + (size_t)blockIdx.z * mn;
#pragma unroll
        for (int m = 0; m < 4; ++m) {
            int row = m0 + wr * 64 + m * 16 + (g << 2);
#pragma unroll
            for (int n = 0; n < 2; ++n) {
                int col = n0 + wc * 32 + n * 16 + fr;
#pragma unroll
                for (int r = 0; r < 4; ++r)
                    op[(size_t)(row + r) * N + col] = acc[m][n][r];
            }
        }
    } else {
#pragma unroll
        for (int m = 0; m < 4; ++m) {
            int row = m0 + wr * 64 + m * 16 + (g << 2);
#pragma unroll
            for (int n = 0; n < 2; ++n) {
                int col = n0 + wc * 32 + n * 16 + fr;
                float bv = bias ? bias[col & bmask] : 0.f;
#pragma unroll
                for (int r = 0; r < 4; ++r) {
                    float v = acc[m][n][r] + bv;
                    v = apply_act(v, act);
                    C[(size_t)(row + r) * N + col] = v;
                }
            }
        }
    }
}

// Fused QKV on the MFMA path: z = which*2 + s (split-K=2), raw partials.
__global__ __launch_bounds__(256) void k_qkv16(const float* __restrict__ A,
                                               const _Float16* __restrict__ LW,
                                               float* __restrict__ part) {
    __shared__ _Float16 Ash[128 * 64];
    __shared__ _Float16 Asl[128 * 64];
    __shared__ _Float16 Bsh[64 * 64];
    __shared__ _Float16 Bsl[64 * 64];
    int which = blockIdx.z >> 1, s2 = blockIdx.z & 1;
    const _Float16* BTh = LW + which * 524288;
    const _Float16* BTl = BTh + 262144;
    int m0 = blockIdx.x * 128, n0 = blockIdx.y * 64;
    int kz = s2 * 256;
    f32x4 acc[4][2];
#pragma unroll
    for (int m = 0; m < 4; ++m)
#pragma unroll
        for (int n = 0; n < 2; ++n)
#pragma unroll
            for (int r = 0; r < 4; ++r) acc[m][n][r] = 0.f;
    mf_core(A + kz, 512, BTh, BTl, 512, m0, n0, kz, 256, acc, Ash, Asl, Bsh, Bsl);
    int tid = threadIdx.x;
    int lane = tid & 63, wv = tid >> 6;
    int wr = wv >> 1, wc = wv & 1;
    int fr = lane & 15, g = lane >> 4;
    float* op = part + (size_t)blockIdx.z * 262144;
#pragma unroll
    for (int m = 0; m < 4; ++m) {
        int row = m0 + wr * 64 + m * 16 + (g << 2);
#pragma unroll
        for (int n = 0; n < 2; ++n) {
            int col = n0 + wc * 32 + n * 16 + fr;
#pragma unroll
            for (int r = 0; r < 4; ++r)
                op[(size_t)(row + r) * 512 + col] = acc[m][n][r];
        }
    }
}

// ---------------------------------------------------------------------------
// fp16x3 MFMA GEMM, A from PRE-SPLIT f16 hi/lo planes (tail chain).
// ---------------------------------------------------------------------------
template <int NT>
__global__ __launch_bounds__(256) void k_gemm16h(
        const _Float16* __restrict__ Ah, const _Float16* __restrict__ Al, int lda,
        const _Float16* __restrict__ BTh, const _Float16* __restrict__ BTl, int ldb,
        const float* __restrict__ bias, unsigned bmask,
        float* __restrict__ C, _Float16* __restrict__ Ch, _Float16* __restrict__ Cl,
        float* __restrict__ part, long mn, int N, int klen, int act) {
    constexpr int BN = NT * 32;
    __shared__ _Float16 Ash[128 * 64];
    __shared__ _Float16 Asl[128 * 64];
    __shared__ _Float16 Bsh[BN * 64];
    __shared__ _Float16 Bsl[BN * 64];
    int tid = threadIdx.x;
    int m0 = blockIdx.x * 128, n0 = blockIdx.y * BN;
    int kz = blockIdx.z * klen;
    int lane = tid & 63, wv = tid >> 6;
    int wr = wv >> 1, wc = wv & 1;
    int fr = lane & 15, g = lane >> 4;

    f32x4 acc[4][NT];
#pragma unroll
    for (int m = 0; m < 4; ++m)
#pragma unroll
        for (int n = 0; n < NT; ++n)
#pragma unroll
            for (int r = 0; r < 4; ++r) acc[m][n][r] = 0.f;

    int nk = klen >> 6;
    for (int t = 0; t < nk; ++t) {
        int k0 = kz + (t << 6);
#pragma unroll
        for (int i2 = 0; i2 < 4; ++i2) {
            int c = tid + 256 * i2;
            int row = c >> 3, s = c & 7;
            size_t go = (size_t)(m0 + row) * lda + k0 + (s << 3);
            f16x8 hv = *(const f16x8*)(Ah + go);
            f16x8 lv = *(const f16x8*)(Al + go);
            int off = row * 64 + ((s ^ (row & 7)) << 3);
            *(f16x8*)(Ash + off) = hv;
            *(f16x8*)(Asl + off) = lv;
        }
#pragma unroll
        for (int i2 = 0; i2 < BN / 32; ++i2) {
            int c = tid + 256 * i2;
            int col = c >> 3, s = c & 7;
            size_t go = (size_t)(n0 + col) * ldb + k0 + (s << 3);
            f16x8 hv = *(const f16x8*)(BTh + go);
            f16x8 lv = *(const f16x8*)(BTl + go);
            int off = col * 64 + ((s ^ (col & 7)) << 3);
            *(f16x8*)(Bsh + off) = hv;
            *(f16x8*)(Bsl + off) = lv;
        }
        __syncthreads();
#pragma unroll
        for (int kk = 0; kk < 2; ++kk) {
            f16x8 ah[4], al4[4], bh[NT], bl[NT];
#pragma unroll
            for (int m = 0; m < 4; ++m) {
                int row = wr * 64 + m * 16 + fr;
                int off = row * 64 + ((((kk << 2) + g) ^ (row & 7)) << 3);
                ah[m] = *(const f16x8*)(Ash + off);
                al4[m] = *(const f16x8*)(Asl + off);
            }
#pragma unroll
            for (int n = 0; n < NT; ++n) {
                int col = wc * (NT * 16) + n * 16 + fr;
                int off = col * 64 + ((((kk << 2) + g) ^ (col & 7)) << 3);
                bh[n] = *(const f16x8*)(Bsh + off);
                bl[n] = *(const f16x8*)(Bsl + off);
            }
#pragma unroll
            for (int m = 0; m < 4; ++m)
#pragma unroll
                for (int n = 0; n < NT; ++n) {
                    acc[m][n] = __builtin_amdgcn_mfma_f32_16x16x32_f16(ah[m], bh[n], acc[m][n], 0, 0, 0);
                    acc[m][n] = __builtin_amdgcn_mfma_f32_16x16x32_f16(ah[m], bl[n], acc[m][n], 0, 0, 0);
                    acc[m][n] = __builtin_amdgcn_mfma_f32_16x16x32_f16(al4[m], bh[n], acc[m][n], 0, 0, 0);
                }
        }
        __syncthreads();
    }
    if (part) {
        float* op = part + (size_t)blockIdx.z * mn;
#pragma unroll
        for (int m = 0; m < 4; ++m) {
            int row = m0 + wr * 64 + m * 16 + (g << 2);
#pragma unroll
            for (int n = 0; n < NT; ++n) {
                int col = n0 + wc * (NT * 16) + n * 16 + fr;
#pragma unroll
                for (int r = 0; r < 4; ++r)
                    op[(size_t)(row + r) * N + col] = acc[m][n][r];
            }
        }
    } else {
#pragma unroll
        for (int m = 0; m < 4; ++m) {
            int row = m0 + wr * 64 + m * 16 + (g << 2);
#pragma unroll
            for (int n = 0; n < NT; ++n) {
                int col = n0 + wc * (NT * 16) + n * 16 + fr;
                float bv = bias ? bias[col & bmask] : 0.f;
#pragma unroll
                for (int r = 0; r < 4; ++r) {
                    float v = acc[m][n][r] + bv;
                    v = apply_act(v, act);
                    size_t idx = (size_t)(row + r) * N + col;
                    if (Cl) {
                        _Float16 hh = (_Float16)v;
                        Ch[idx] = hh;
                        Cl[idx] = (_Float16)(v - (float)hh);
                    } else {
                        C[idx] = v;
                    }
                }
            }
        }
    }
}

// ---------------------------------------------------------------------------
// fp32 GEMM core (kept for pf/fo/ro RVQ gemms)
// ---------------------------------------------------------------------------
template <int TM>
__device__ __forceinline__ void gemm_core(const float* __restrict__ A, int lda,
                                          const float* __restrict__ B, int N,
                                          int klen, int m0, int n0,
                                          float (&acc)[TM / 16][4]) {
    constexpr int RM = TM / 16;
    constexpr int AR = TM * 16 / 256;
    __shared__ float As[2][16][TM + 4];
    __shared__ float Bs[2][16][64];
    int tid = threadIdx.x;
    int tx = tid & 15, ty = tid >> 4;
    int bc = tid & 63, br0 = tid >> 6;
    int arow[AR], akk[AR];
#pragma unroll
    for (int i = 0; i < AR; i++) { int idx = tid + 256 * i; arow[i] = idx >> 4; akk[i] = idx & 15; }
    float areg[AR], breg[4];
#pragma unroll
    for (int i = 0; i < AR; i++) areg[i] = A[(size_t)(m0 + arow[i]) * lda + akk[i]];
#pragma unroll
    for (int i = 0; i < 4; i++) breg[i] = B[(size_t)(br0 + 4 * i) * N + n0 + bc];
#pragma unroll
    for (int i = 0; i < AR; i++) As[0][akk[i]][arow[i]] = areg[i];
#pragma unroll
    for (int i = 0; i < 4; i++) Bs[0][br0 + 4 * i][bc] = breg[i];
    __syncthreads();
    int nk = klen >> 4;
    for (int t = 0; t < nk; t++) {
        int cur = t & 1;
        if (t + 1 < nk) {
            int k0 = (t + 1) << 4;
#pragma unroll
            for (int i = 0; i < AR; i++) areg[i] = A[(size_t)(m0 + arow[i]) * lda + k0 + akk[i]];
#pragma unroll
            for (int i = 0; i < 4; i++) breg[i] = B[(size_t)(k0 + br0 + 4 * i) * N + n0 + bc];
        }
#pragma unroll
        for (int kk = 0; kk < 16; kk++) {
            float a[RM], b[4];
#pragma unroll
            for (int i = 0; i < RM; i++) a[i] = As[cur][kk][ty * RM + i];
#pragma unroll
            for (int j = 0; j < 4; j++) b[j] = Bs[cur][kk][tx * 4 + j];
#pragma unroll
            for (int i = 0; i < RM; i++)
#pragma unroll
                for (int j = 0; j < 4; j++) acc[i][j] += a[i] * b[j];
        }
        if (t + 1 < nk) {
            int nxt = cur ^ 1;
#pragma unroll
            for (int i = 0; i < AR; i++) As[nxt][akk[i]][arow[i]] = areg[i];
#pragma unroll
            for (int i = 0; i < 4; i++) Bs[nxt][br0 + 4 * i][bc] = breg[i];
            __syncthreads();
        }
    }
}

template <int TM>
__global__ __launch_bounds__(256) void k_gemm2(const float* __restrict__ A, int lda,
                                               const float* __restrict__ B,
                                               const float* __restrict__ bias, unsigned bmask,
                                               const float* __restrict__ res,
                                               const float* __restrict__ scale,
                                               float* __restrict__ C,
                                               float* __restrict__ part, long mn,
                                               int N, int klen, int act) {
    constexpr int RM = TM / 16;
    float acc[RM][4] = {};
    int m0 = blockIdx.x * TM, n0 = blockIdx.y * 64;
    int kz = blockIdx.z * klen;
    gemm_core<TM>(A + kz, lda, B + (size_t)kz * N, N, klen, m0, n0, acc);
    int tid = threadIdx.x;
    int tx = tid & 15, ty = tid >> 4;
    if (part) {
        float* out = part + (size_t)blockIdx.z * mn;
#pragma unroll
        for (int i = 0; i < RM; i++)
#pragma unroll
            for (int j = 0; j < 4; j++)
                out[(size_t)(m0 + ty * RM + i) * N + n0 + tx * 4 + j] = acc[i][j];
    } else {
#pragma unroll
        for (int i = 0; i < RM; i++) {
            int row = m0 + ty * RM + i;
#pragma unroll
            for (int j = 0; j < 4; j++) {
                int col = n0 + tx * 4 + j;
                float v = acc[i][j];
                if (bias) v += bias[col & bmask];
                v = apply_act(v, act);
                if (scale) v *= scale[col];
                if (res) v += res[(size_t)row * N + col];
                C[(size_t)row * N + col] = v;
            }
        }
    }
}

// ---------------------------------------------------------------------------
// Split-K reduce + epilogue (bias -> act -> scale -> res), fp32 out
// ---------------------------------------------------------------------------
__global__ __launch_bounds__(256) void k_reduce(const float* __restrict__ part, long mn, int S,
                                                const float* __restrict__ bias, unsigned bmask,
                                                const float* __restrict__ res,
                                                const float* __restrict__ scale,
                                                float* __restrict__ C, int N, int act) {
    long idx = ((long)blockIdx.x * 256 + threadIdx.x) * 4;
    if (idx >= mn) return;
    float4 v = *(const float4*)(part + idx);
    for (int s2 = 1; s2 < S; s2++) {
        float4 u = *(const float4*)(part + (size_t)s2 * mn + idx);
        v.x += u.x; v.y += u.y; v.z += u.z; v.w += u.w;
    }
    int col = (int)(idx % N);
    float vv[4] = {v.x, v.y, v.z, v.w};
#pragma unroll
    for (int j = 0; j < 4; j++) {
        float t = vv[j];
        int c = col + j;
        if (bias) t += bias[c & bmask];
        t = apply_act(t, act);
        if (scale) t *= scale[c];
        if (res) t += res[idx + j];
        vv[j] = t;
    }
    *(float4*)(C + idx) = make_float4(vv[0], vv[1], vv[2], vv[3]);
}

// Split-K reduce writing f16 hi/lo planes (bias -> act -> split)
__global__ __launch_bounds__(256) void k_reduce_h(const float* __restrict__ part, long mn, int S,
                                                  const float* __restrict__ bias, unsigned bmask,
                                                  _Float16* __restrict__ Ch,
                                                  _Float16* __restrict__ Cl, int N, int act) {
    long idx = ((long)blockIdx.x * 256 + threadIdx.x) * 4;
    if (idx >= mn) return;
    float4 v = *(const float4*)(part + idx);
    for (int s2 = 1; s2 < S; s2++) {
        float4 u = *(const float4*)(part + (size_t)s2 * mn + idx);
        v.x += u.x; v.y += u.y; v.z += u.z; v.w += u.w;
    }
    int col = (int)(idx % N);
    float vv[4] = {v.x, v.y, v.z, v.w};
    f16x4 h, l;
#pragma unroll
    for (int j = 0; j < 4; j++) {
        float t = vv[j];
        if (bias) t += bias[(col + j) & bmask];
        t = apply_act(t, act);
        _Float16 hh = (_Float16)t;
        h[j] = hh;
        l[j] = (_Float16)(t - (float)hh);
    }
    *(f16x4*)(Ch + idx) = h;
    *(f16x4*)(Cl + idx) = l;
}

__global__ __launch_bounds__(256) void k_reduce_qkv(const float* __restrict__ part,
                                                    float* __restrict__ q,
                                                    float* __restrict__ k,
                                                    float* __restrict__ v) {
    const long mn = 262144;
    int w = blockIdx.y;
    long idx = ((long)blockIdx.x * 256 + threadIdx.x) * 4;
    float4 a = *(const float4*)(part + (size_t)(2 * w) * mn + idx);
    float4 b = *(const float4*)(part + (size_t)(2 * w + 1) * mn + idx);
    float* C = w == 0 ? q : (w == 1 ? k : v);
    *(float4*)(C + idx) = make_float4(a.x + b.x, a.y + b.y, a.z + b.z, a.w + b.w);
}

// ---------------------------------------------------------------------------
// RMSNorm rows of x[M,N]
// ---------------------------------------------------------------------------
__global__ __launch_bounds__(256) void k_rms(const float* __restrict__ x,
                                             const float* __restrict__ g,
                                             float* __restrict__ y, int N) {
    int row = blockIdx.x;
    const float* xr = x + (size_t)row * N;
    int tid = threadIdx.x;
    float s = 0.f;
    for (int i = tid; i < N; i += 256) { float v = xr[i]; s += v * v; }
#pragma unroll
    for (int off = 32; off; off >>= 1) s += __shfl_xor(s, off);
    __shared__ float red[4];
    if ((tid & 63) == 0) red[tid >> 6] = s;
    __syncthreads();
    s = red[0] + red[1] + red[2] + red[3];
    float r = 1.0f / sqrtf(s / (float)N + 1e-6f);
    for (int i = tid; i < N; i += 256) y[(size_t)row * N + i] = xr[i] * r * g[i];
}

// ---------------------------------------------------------------------------
// Fused qk-norm + RoPE (cos/sin from precomputed table)
// ---------------------------------------------------------------------------
__global__ void k_qkrope2(float* __restrict__ q, float* __restrict__ k,
                          const float* __restrict__ gq, const float* __restrict__ gk,
                          const float* __restrict__ tab) {
    int bid = blockIdx.x;
    int t = bid >> 3, h = bid & 7;
    int d = threadIdx.x;
    float* p = (blockIdx.y == 0 ? q : k) + (size_t)t * D_DIM + h * HD;
    const float* g = blockIdx.y == 0 ? gq : gk;
    float val = p[d];
    float s = val * val;
#pragma unroll
    for (int off = 32; off; off >>= 1) s += __shfl_xor(s, off);
    float r = 1.0f / sqrtf(s * (1.0f / 64.0f) + 1e-6f);
    float y = val * r * g[d];
    int dm = d & 31;
    float c = tab[t * 32 + dm];
    float sn = tab[16384 + t * 32 + dm];
    float partner = __shfl_xor(y, 32);
    float out = (d < 32) ? (y * c - partner * sn) : (y * c + partner * sn);
    p[d] = out;
}

// ---------------------------------------------------------------------------
// MFMA flash attention (fp16x3 hi/lo = ~fp32 precision).
// ---------------------------------------------------------------------------
__global__ __launch_bounds__(128) void k_attn_mf(const float* __restrict__ q,
                                                 const float* __restrict__ k,
                                                 const float* __restrict__ v,
                                                 float* __restrict__ o) {
    __shared__ _Float16 Ph[2][16][32];
    __shared__ _Float16 Pl[2][16][32];
    __shared__ float mM[16], lM[16], OM[16][64];
    int h = blockIdx.x >> 5, qt = blockIdx.x & 31;
    int qr0 = qt << 4;
    int tid = threadIdx.x;
    int s = tid >> 6, lane = tid & 63;
    int fr = lane & 15, g = lane >> 4;
    int hoff = h * 64;

    f16x8 qh[2], ql[2];
    {
        const float* qp = q + (size_t)(qr0 + fr) * 512 + hoff + g * 8;
#pragma unroll
        for (int c = 0; c < 2; ++c) {
            float4 v0 = *(const float4*)(qp + c * 32);
            float4 v1 = *(const float4*)(qp + c * 32 + 4);
            float vv[8] = {v0.x, v0.y, v0.z, v0.w, v1.x, v1.y, v1.z, v1.w};
#pragma unroll
            for (int j = 0; j < 8; ++j) {
                float x = vv[j] * 0.125f;
                _Float16 hh = (_Float16)x;
                qh[c][j] = hh;
                ql[c][j] = (_Float16)(x - (float)hh);
            }
        }
    }

    float m_run = -3.4e38f, l_run = 0.f;
    f32x4 accO[4];
#pragma unroll
    for (int dt = 0; dt < 4; ++dt)
#pragma unroll
        for (int r = 0; r < 4; ++r) accO[dt][r] = 0.f;

    int nkt = (qr0 + 47) >> 5;
    for (int kt = s; kt < nkt; kt += 2) {
        int c0 = kt << 5;
        float sv[2][4];
        float mx = -3.4e38f;
#pragma unroll
        for (int t2 = 0; t2 < 2; ++t2) {
            const float* kp = k + (size_t)(c0 + t2 * 16 + fr) * 512 + hoff + g * 8;
            f16x8 kh[2], kl[2];
#pragma unroll
            for (int c = 0; c < 2; ++c) {
                float4 v0 = *(const float4*)(kp + c * 32);
                float4 v1 = *(const float4*)(kp + c * 32 + 4);
                float vv[8] = {v0.x, v0.y, v0.z, v0.w, v1.x, v1.y, v1.z, v1.w};
#pragma unroll
                for (int j = 0; j < 8; ++j) {
                    _Float16 hh = (_Float16)vv[j];
                    kh[c][j] = hh;
                    kl[c][j] = (_Float16)(vv[j] - (float)hh);
                }
            }
            f32x4 a;
#pragma unroll
            for (int r = 0; r < 4; ++r) a[r] = 0.f;
#pragma unroll
            for (int c = 0; c < 2; ++c) {
                a = __builtin_amdgcn_mfma_f32_16x16x32_f16(kh[c], qh[c], a, 0, 0, 0);
                a = __builtin_amdgcn_mfma_f32_16x16x32_f16(kh[c], ql[c], a, 0, 0, 0);
                a = __builtin_amdgcn_mfma_f32_16x16x32_f16(kl[c], qh[c], a, 0, 0, 0);
            }
#pragma unroll
            for (int r = 0; r < 4; ++r) {
                int key = c0 + t2 * 16 + g * 4 + r;
                float x = (key <= qr0 + fr) ? a[r] : -3.4e38f;
                sv[t2][r] = x;
                mx = fmaxf(mx, x);
            }
        }
        mx = fmaxf(mx, __shfl_xor(mx, 16));
        mx = fmaxf(mx, __shfl_xor(mx, 32));
        float m_new = fmaxf(m_run, mx);
        float alpha = __expf(m_run - m_new);
        l_run *= alpha;
        float ar[4];
#pragma unroll
        for (int r = 0; r < 4; ++r) ar[r] = __shfl(alpha, g * 4 + r);
#pragma unroll
        for (int dt = 0; dt < 4; ++dt)
#pragma unroll
            for (int r = 0; r < 4; ++r) accO[dt][r] *= ar[r];
        float psum = 0.f;
#pragma unroll
        for (int t2 = 0; t2 < 2; ++t2) {
            f16x4 ph4, pl4;
#pragma unroll
            for (int r = 0; r < 4; ++r) {
                float p = __expf(sv[t2][r] - m_new);
                psum += p;
                _Float16 hh = (_Float16)p;
                ph4[r] = hh;
                pl4[r] = (_Float16)(p - (float)hh);
            }
            *(f16x4*)(&Ph[s][fr][t2 * 16 + g * 4]) = ph4;
            *(f16x4*)(&Pl[s][fr][t2 * 16 + g * 4]) = pl4;
        }
        psum += __shfl_xor(psum, 16);
        psum += __shfl_xor(psum, 32);
        l_run += psum;
        m_run = m_new;
        f16x8 pah = *(const f16x8*)(&Ph[s][fr][g * 8]);
        f16x8 pal = *(const f16x8*)(&Pl[s][fr][g * 8]);
#pragma unroll
        for (int dt = 0; dt < 4; ++dt) {
            const float* vp = v + (size_t)(c0 + g * 8) * 512 + hoff + dt * 16 + fr;
            f16x8 bh, bl;
#pragma unroll
            for (int j = 0; j < 8; ++j) {
                float x = vp[(size_t)j * 512];
                _Float16 hh = (_Float16)x;
                bh[j] = hh;
                bl[j] = (_Float16)(x - (float)hh);
            }
            accO[dt] = __builtin_amdgcn_mfma_f32_16x16x32_f16(pah, bh, accO[dt], 0, 0, 0);
            accO[dt] = __builtin_amdgcn_mfma_f32_16x16x32_f16(pah, bl, accO[dt], 0, 0, 0);
            accO[dt] = __builtin_amdgcn_mfma_f32_16x16x32_f16(pal, bh, accO[dt], 0, 0, 0);
        }
    }
    if (s == 1) {
        if (g == 0) { mM[fr] = m_run; lM[fr] = l_run; }
#pragma unroll
        for (int dt = 0; dt < 4; ++dt)
#pragma unroll
            for (int r = 0; r < 4; ++r)
                OM[g * 4 + r][dt * 16 + fr] = accO[dt][r];
    }
    __syncthreads();
    if (s == 0) {
        float m1 = mM[fr], l1 = lM[fr];
        float mf = fmaxf(m_run, m1);
        float a0 = __expf(m_run - mf), a1 = __expf(m1 - mf);
        float lf = l_run * a0 + l1 * a1;
        float inv = 1.0f / lf;
        float a0r[4], a1r[4], invr[4];
#pragma unroll
        for (int r = 0; r < 4; ++r) {
            a0r[r] = __shfl(a0, g * 4 + r);
            a1r[r] = __shfl(a1, g * 4 + r);
            invr[r] = __shfl(inv, g * 4 + r);
        }
#pragma unroll
        for (int dt = 0; dt < 4; ++dt)
#pragma unroll
            for (int r = 0; r < 4; ++r) {
                float ov = (accO[dt][r] * a0r[r] + OM[g * 4 + r][dt * 16 + fr] * a1r[r]) * invr[r];
                o[(size_t)(qr0 + g * 4 + r) * 512 + hoff + dt * 16 + fr] = ov;
            }
    }
}

// ---------------------------------------------------------------------------
// Final conv: Cin=32 -> 1, K=7 SAME, clip
// ---------------------------------------------------------------------------
__global__ __launch_bounds__(256) void k_conv_fin(const float* __restrict__ x,
                                                  const float* __restrict__ w,
                                                  const float* __restrict__ b,
                                                  float* __restrict__ y, int n) {
    __shared__ float xs[262 * 33];
    __shared__ float wsm[224];
    int tid = threadIdx.x;
    int o0 = blockIdx.x * 256;
    for (int i = tid; i < 262 * 32; i += 256) {
        int r = i >> 5, c = i & 31;
        int t = o0 - 3 + r;
        xs[r * 33 + c] = (t >= 0 && t < n) ? x[(size_t)t * 32 + c] : 0.f;
    }
    if (tid < 224) wsm[tid] = w[tid];
    __syncthreads();
    float acc = b[0];
#pragma unroll
    for (int kk = 0; kk < 7; kk++)
#pragma unroll
        for (int ci = 0; ci < 32; ci++)
            acc += xs[(tid + kk) * 33 + ci] * wsm[kk * 32 + ci];
    y[o0 + tid] = fminf(fmaxf(acc, -1.f), 1.f);
}

// ---------------------------------------------------------------------------
// Host helper (fp32 path, RVQ only)
// ---------------------------------------------------------------------------
static inline void gemmS64(hipStream_t st, const float* A, int lda, const float* B,
                           const float* bias, unsigned bmask, const float* res,
                           const float* scale, float* C, float* part,
                           int M, int N, int K, int S, int act) {
    long mn = (long)M * N;
    if (S > 1) {
        k_gemm2<64><<<dim3(M / 64, N / 64, S), 256, 0, st>>>(
            A, lda, B, nullptr, 0, nullptr, nullptr, nullptr, part, mn, N, K / S, 0);
        k_reduce<<<dim3((int)(mn / 1024)), 256, 0, st>>>(
            part, mn, S, bias, bmask, res, scale, C, N, act);
    } else {
        k_gemm2<64><<<dim3(M / 64, N / 64, 1), 256, 0, st>>>(
            A, lda, B, bias, bmask, res, scale, C, nullptr, mn, N, K, act);
    }
}

extern "C" void kernel_launch(void* const* d_in, const int* in_sizes, int n_in,
                              void* d_out, int out_size, void* d_ws, size_t ws_size,
                              hipStream_t stream) {
    int i = 0;
    const int*   codes     = (const int*)  d_in[i++];
    const float* emb_first = (const float*)d_in[i++];
    const float* pf_w      = (const float*)d_in[i++];
    const float* pf_b      = (const float*)d_in[i++];
    const float* fo_w      = (const float*)d_in[i++];
    const float* fo_b      = (const float*)d_in[i++];
    const float* emb_rest  = (const float*)d_in[i++];
    const float* pr_w      = (const float*)d_in[i++];
    const float* pr_b      = (const float*)d_in[i++];
    const float* ro_w      = (const float*)d_in[i++];
    const float* ro_b      = (const float*)d_in[i++];
    const float* pre_w     = (const float*)d_in[i++];
    const float* pre_b     = (const float*)d_in[i++];
    const float* in_w      = (const float*)d_in[i++];
    const float* in_b      = (const float*)d_in[i++];
    const float* ln1       = (const float*)d_in[i++];
    const float* qw        = (const float*)d_in[i++];
    const float* kw        = (const float*)d_in[i++];
    const float* vw        = (const float*)d_in[i++];
    const float* ow        = (const float*)d_in[i++];
    const float* qn        = (const float*)d_in[i++];
    const float* kn        = (const float*)d_in[i++];
    const float* ls_a      = (const float*)d_in[i++];
    const float* ln2       = (const float*)d_in[i++];
    const float* w1        = (const float*)d_in[i++];
    const float* w2        = (const float*)d_in[i++];
    const float* ls_m      = (const float*)d_in[i++];
    const float* fn_w      = (const float*)d_in[i++];
    const float* out_w     = (const float*)d_in[i++];
    const float* out_b     = (const float*)d_in[i++];
    const float* up_w      = (const float*)d_in[i++];
    const float* up_b      = (const float*)d_in[i++];
    const float* dec0_w    = (const float*)d_in[i++];
    const float* dec0_b    = (const float*)d_in[i++];
    const float* dw1       = (const float*)d_in[i++];
    const float* db1       = (const float*)d_in[i++];
    const float* dw2       = (const float*)d_in[i++];
    const float* db2       = (const float*)d_in[i++];
    const float* dw3       = (const float*)d_in[i++];
    const float* db3       = (const float*)d_in[i++];
    const float* dw4       = (const float*)d_in[i++];
    const float* db4       = (const float*)d_in[i++];
    const float* fin_w     = (const float*)d_in[i++];
    const float* fin_b     = (const float*)d_in[i++];

    float* ws = (float*)d_ws;
    float* outp = (float*)d_out;

    float* qf_pre   = ws + WS_QFPRE;
    float* G        = ws + WS_G;
    float* qf       = ws + WS_QF;
    float* tA       = ws + WS_TA;
    float* hidden   = ws + WS_HID;
    float* conv_out = ws + WS_CONV;
    float* h        = ws + WS_H;
    float* x        = ws + WS_X;
    float* qb       = ws + WS_QB;
    float* kb       = ws + WS_KB;
    float* vb       = ws + WS_VB;
    float* attnb    = ws + WS_ATT;
    float* ff       = ws + WS_FF;
    float* bias_sum = ws + WS_BSUM;
    float* houtp    = ws + WS_HOUT;
    float* t4       = ws + WS_T4;
    float* part     = ws + WS_PART;
    float* ropetab  = ws + WS_ROPE;

    // f16 plane data pointers (tail)
    _Float16* up16h = (_Float16*)(ws + UP16H_D);
    _Float16* up16l = (_Float16*)(ws + UP16L_D);
    _Float16* dec16h = (_Float16*)(ws + DEC16H_D);
    _Float16* dec16l = (_Float16*)(ws + DEC16L_D);
    _Float16* t1h = (_Float16*)(ws + T1H_D);
    _Float16* t1l = (_Float16*)(ws + T1L_D);
    _Float16* t2h = (_Float16*)(ws + T2H_D);
    _Float16* t2l = (_Float16*)(ws + T2L_D);
    _Float16* t3h = (_Float16*)(ws + T3H_D);
    _Float16* t3l = (_Float16*)(ws + T3L_D);

    // f16 hi/lo transposed weight planes (static)
    _Float16* BTup_h = (_Float16*)(ws + WS_W2UP);   _Float16* BTup_l = BTup_h + 2048 * 3072;
    _Float16* BTd1_h = (_Float16*)(ws + WS_W2D1);   _Float16* BTd1_l = BTd1_h + 2048 * 1536;
    _Float16* BTd2_h = (_Float16*)(ws + WS_W2D2);   _Float16* BTd2_l = BTd2_h + 768 * 768;
    _Float16* BTd3_h = (_Float16*)(ws + WS_W2D3);   _Float16* BTd3_l = BTd3_h + 320 * 384;
    _Float16* BTd4_h = (_Float16*)(ws + WS_W2D4);   _Float16* BTd4_l = BTd4_h + 128 * 192;
    _Float16* BTd0_h = (_Float16*)(ws + WS_DEC0B16);_Float16* BTd0_l = BTd0_h + 512 * 7168;
    _Float16* BTpr_h = (_Float16*)(ws + WS_BTPR);   _Float16* BTpr_l = BTpr_h + 1024 * 3840;

    // Scratch plane region at ws+0 (dead RVQ buffers): pre_w / in_w / per-layer
    // weights / out_w, strictly sequenced.
    _Float16* LW = (_Float16*)ws;

    // --- prep ---
    k_zero_guards<<<15, 256, 0, stream>>>(ws);
    k_rope_tab<<<64, 256, 0, stream>>>(ropetab);
    k_wt16<<<dim3(32, 24), 256, 0, stream>>>(up_w, BTup_h, BTup_l, 1024, 1024, 2, 2);
    k_wt16<<<dim3(32, 12), 256, 0, stream>>>(dw1, BTd1_h, BTd1_l, 512, 256, 8, 11);
    k_wt16<<<dim3(12, 6), 256, 0, stream>>>(dw2, BTd2_h, BTd2_l, 256, 128, 6, 8);
    k_wt16<<<dim3(5, 3), 256, 0, stream>>>(dw3, BTd3_h, BTd3_l, 128, 64, 5, 7);
    k_wt16<<<dim3(2, 2), 256, 0, stream>>>(dw4, BTd4_h, BTd4_l, 64, 32, 4, 5);
    k_bt16<<<dim3(8, 56), 256, 0, stream>>>(dec0_w, BTd0_h, BTd0_l, 7168, 512);
    k_bt16<<<dim3(16, 30), 256, 0, stream>>>(pr_w, BTpr_h, BTpr_l, 3840, 1024);

    // --- RVQ decode ---
    k_gather<<<8192, 256, 0, stream>>>(codes, emb_first, emb_rest, qf_pre, G);
    k_bias_sum<<<4, 256, 0, stream>>>(pr_b, bias_sum);
    gemmS64(stream, qf_pre, 256, pf_w, pf_b, ~0u, nullptr, nullptr, tA, part, 512, 1024, 256, 2, 0);
    gemmS64(stream, tA, 1024, fo_w, fo_b, ~0u, nullptr, nullptr, qf, part, 512, 1024, 1024, 4, 0);
    k_gemm16<<<dim3(4, 16, 4), 256, 0, stream>>>(G, 3840, BTpr_h, BTpr_l, 3840,
            nullptr, 0, nullptr, part, 524288L, 1024, 960, 0);
    k_reduce<<<512, 256, 0, stream>>>(part, 524288L, 4, bias_sum, ~0u, nullptr, nullptr,
            tA, 1024, 0);
    gemmS64(stream, tA, 1024, ro_w, ro_b, ~0u, qf, nullptr, hidden, part, 512, 1024, 1024, 4, 0);
    // ws[0..3.15M] now dead (qf_pre, G, qf, tA consumed)

    // --- causal pre-conv (k=3) via MFMA windowed GEMM ---
    // pre_w [3072][1024] -> BT planes at LW (h: 0, l: +3145728 f16)
    k_bt16<<<dim3(16, 24), 256, 0, stream>>>(pre_w, LW, LW + 3145728, 3072, 1024);
    k_gemm16<<<dim3(4, 16, 4), 256, 0, stream>>>(hidden - 2048, 1024, LW, LW + 3145728, 3072,
            nullptr, 0, nullptr, part, 524288L, 1024, 768, 0);
    k_reduce<<<512, 256, 0, stream>>>(part, 524288L, 4, pre_b, ~0u, nullptr, nullptr,
            conv_out, 1024, 0);

    // --- transformer input proj (MFMA) ---
    k_bt16<<<dim3(8, 8), 256, 0, stream>>>(in_w, LW, LW + 524288, 1024, 512);
    k_gemm16<<<dim3(4, 8, 2), 256, 0, stream>>>(conv_out, 1024, LW, LW + 524288, 1024,
            nullptr, 0, nullptr, part, 262144L, 512, 512, 0);
    k_reduce<<<256, 256, 0, stream>>>(part, 262144L, 2, in_b, ~0u, nullptr, nullptr,
            h, 512, 0);

    // --- 8 transformer layers (all GEMMs on MFMA path) ---
    for (int l = 0; l < NL; l++) {
        const float* qw_l = qw + (size_t)l * D_DIM * D_DIM;
        const float* kw_l = kw + (size_t)l * D_DIM * D_DIM;
        const float* vw_l = vw + (size_t)l * D_DIM * D_DIM;
        const float* ow_l = ow + (size_t)l * D_DIM * D_DIM;
        const float* w1_l = w1 + (size_t)l * D_DIM * FF_D;
        const float* w2_l = w2 + (size_t)l * FF_D * D_DIM;

        k_ltw<<<384, 256, 0, stream>>>(qw_l, kw_l, vw_l, ow_l, w1_l, w2_l, LW);
        k_rms<<<512, 256, 0, stream>>>(h, ln1 + l * D_DIM, x, D_DIM);
        k_qkv16<<<dim3(4, 8, 6), 256, 0, stream>>>(x, LW, part);
        k_reduce_qkv<<<dim3(256, 3), 256, 0, stream>>>(part, qb, kb, vb);
        k_qkrope2<<<dim3(T_LEN * NH, 2), 64, 0, stream>>>(qb, kb, qn + l * HD, kn + l * HD, ropetab);
        k_attn_mf<<<256, 128, 0, stream>>>(qb, kb, vb, attnb);
        // o-proj: split-K=2 + epilogue (scale ls_a, res h)
        k_gemm16<<<dim3(4, 8, 2), 256, 0, stream>>>(attnb, 512, LW + 1572864, LW + 1835008, 512,
                nullptr, 0, nullptr, part, 262144L, 512, 256, 0);
        k_reduce<<<256, 256, 0, stream>>>(part, 262144L, 2, nullptr, 0, h, ls_a + l * D_DIM,
                h, 512, 0);
        k_rms<<<512, 256, 0, stream>>>(h, ln2 + l * D_DIM, x, D_DIM);
        // w1: direct write, gelu
        k_gemm16<<<dim3(4, 32, 1), 256, 0, stream>>>(x, 512, LW + 2097152, LW + 3145728, 512,
                nullptr, 0, ff, nullptr, 0L, 2048, 512, 1);
        // w2: split-K=4 + epilogue (scale ls_m, res h)
        k_gemm16<<<dim3(4, 8, 4), 256, 0, stream>>>(ff, 2048, LW + 4194304, LW + 5242880, 2048,
                nullptr, 0, nullptr, part, 262144L, 512, 512, 0);
        k_reduce<<<256, 256, 0, stream>>>(part, 262144L, 4, nullptr, 0, h, ls_m + l * D_DIM,
                h, 512, 0);
    }

    // --- final norm + out proj (MFMA) ---
    k_rms<<<512, 256, 0, stream>>>(h, fn_w, x, D_DIM);
    k_bt16<<<dim3(16, 4), 256, 0, stream>>>(out_w, LW, LW + 524288, 512, 1024);
    k_gemm16<<<dim3(4, 16, 1), 256, 0, stream>>>(x, 512, LW, LW + 524288, 512,
            out_b, ~0u, houtp, nullptr, 0L, 1024, 512, 0);

    // --- upsample x2 convT (fp32 A), elu; split-K=2 -> f16 planes ---
    k_gemm16<<<dim3(4, 32, 2), 256, 0, stream>>>(houtp - 1024, 1024, BTup_h, BTup_l, 3072,
            nullptr, 0, nullptr, part, 1048576L, 2048, 1536, 0);
    k_reduce_h<<<1024, 256, 0, stream>>>(part, 1048576L, 2, up_b, 1023u,
            up16h, up16l, 2048, 2);

    // --- dec0 conv k=7 SAME (plane A), elu; split-K=8 -> f16 planes ---
    k_gemm16h<4><<<dim3(8, 4, 8), 256, 0, stream>>>(up16h - 3072, up16l - 3072, 1024,
            BTd0_h, BTd0_l, 7168, nullptr, 0, nullptr, nullptr, nullptr,
            part, 524288L, 512, 896, 0);
    k_reduce_h<<<512, 256, 0, stream>>>(part, 524288L, 8, dec0_b, ~0u,
            dec16h, dec16l, 512, 2);
    k_zero2<<<8, 256, 0, stream>>>(ws);

    // --- SEANet convT chain (plane A -> plane out), elu ---
    k_gemm16h<2><<<dim3(8, 32, 1), 256, 0, stream>>>(dec16h - 512, dec16l - 512, 512,
            BTd1_h, BTd1_l, 1536, db1, 255u, nullptr, t1h, t1l, nullptr, 0L, 2048, 1536, 2);
    k_gemm16h<4><<<dim3(64, 6, 1), 256, 0, stream>>>(t1h - 256, t1l - 256, 256,
            BTd2_h, BTd2_l, 768, db2, 127u, nullptr, t2h, t2l, nullptr, 0L, 768, 768, 2);
    k_gemm16h<2><<<dim3(384, 5, 1), 256, 0, stream>>>(t2h - 128, t2l - 128, 128,
            BTd3_h, BTd3_l, 384, db3, 63u, nullptr, t3h, t3l, nullptr, 0L, 320, 384, 2);
    k_gemm16h<4><<<dim3(1920, 1, 1), 256, 0, stream>>>(t3h - 64, t3l - 64, 64,
            BTd4_h, BTd4_l, 192, db4, 31u, t4, nullptr, nullptr, nullptr, 0L, 128, 192, 2);

    // --- final conv ---
    k_conv_fin<<<983040 / 256, 256, 0, stream>>>(t4, fin_w, fin_b, outp, 983040);
}